// Round 1
// baseline (1673.232 us; speedup 1.0000x reference)
//
#include <hip/hip_runtime.h>
#include <hip/hip_bf16.h>

#define NN 100000   // nodes
#define NE 800000   // edges (without self loops)
#define E2 900000   // edges + self loops
#define F  128      // KGE
#define NB 8        // batch
#define SEQ 1024
#define HID 1024
#define DWN 256
#define TP 32

// ---------------- batch offsets from sorted batch_ids ----------------
__global__ void k_offsets(const int* __restrict__ bids, int* __restrict__ offs) {
    int n = blockIdx.x * 256 + threadIdx.x;
    if (n >= NN) return;
    int b = bids[n];
    if (n == 0) offs[0] = 0;
    else if (bids[n - 1] != b) offs[b] = n;
    if (n == NN - 1) offs[b + 1] = NN;
}

// ---------------- embedding gather: x[n] = emb[graph_x[n]] ----------------
__global__ void k_embed(const int* __restrict__ gx, const float* __restrict__ emb,
                        float* __restrict__ x) {
    int i = blockIdx.x * 256 + threadIdx.x;   // over NN*32 float4 chunks
    int n = i >> 5, c = i & 31;
    float4 v = ((const float4*)(emb + (size_t)gx[n] * F))[c];
    ((float4*)(x + (size_t)n * F))[c] = v;
}

// ---------------- CSR build ----------------
__global__ void k_hist(const int* __restrict__ ei, int* __restrict__ counts) {
    int e = blockIdx.x * 256 + threadIdx.x;
    if (e >= E2) return;
    int dst = (e < NE) ? ei[NE + e] : (e - NE);
    atomicAdd(&counts[dst], 1);
}

__global__ void k_bsum(const int* __restrict__ counts, int* __restrict__ bsum) {
    __shared__ int red[256];
    int b = blockIdx.x, t = threadIdx.x;
    int base = b * 500;
    int s = 0;
    for (int i = t; i < 500; i += 256) s += counts[base + i];
    red[t] = s; __syncthreads();
    for (int o = 128; o > 0; o >>= 1) { if (t < o) red[t] += red[t + o]; __syncthreads(); }
    if (t == 0) bsum[b] = red[0];
}

__global__ void k_boff(const int* __restrict__ bsum, int* __restrict__ boff) {
    if (threadIdx.x == 0) {
        int r = 0;
        for (int i = 0; i < 200; i++) { boff[i] = r; r += bsum[i]; }
        boff[200] = r;
    }
}

__global__ void k_indptr(const int* __restrict__ counts, const int* __restrict__ boff,
                         int* __restrict__ indptr, int* __restrict__ cursor) {
    int b = blockIdx.x;
    if (threadIdx.x != 0) return;
    int r = boff[b];
    int base = b * 500;
    for (int i = 0; i < 500; i++) {
        int gi = base + i;
        indptr[gi] = r; cursor[gi] = r;
        r += counts[gi];
    }
    if (b == 199) indptr[NN] = r;
}

__global__ void k_scatter(const int* __restrict__ ei, int* __restrict__ cursor,
                          int* __restrict__ srcs) {
    int e = blockIdx.x * 256 + threadIdx.x;
    if (e >= E2) return;
    int src, dst;
    if (e < NE) { src = ei[e]; dst = ei[NE + e]; }
    else        { src = dst = e - NE; }
    int pos = atomicAdd(&cursor[dst], 1);
    srcs[pos] = src;
}

// ---------------- h = x @ W; hs_src = h.a_s; hs_dst = h.a_d (fused) ----------------
__global__ __launch_bounds__(256) void k_gemm(
    const float* __restrict__ x, const float* __restrict__ W,
    const float* __restrict__ a_s, const float* __restrict__ a_d,
    float* __restrict__ h, float* __restrict__ hs_src, float* __restrict__ hs_dst) {
    int wave = threadIdx.x >> 6, lane = threadIdx.x & 63;
    int n = blockIdx.x * 4 + wave;
    if (n >= NN) return;
    const float* xr = x + (size_t)n * F;
    float xa = xr[lane], xb = xr[64 + lane];
    const float2* W2 = (const float2*)W;
    float accx = 0.f, accy = 0.f;
    #pragma unroll 16
    for (int k = 0; k < 64; k++) {
        float xv = __shfl(xa, k);
        float2 w = W2[k * 64 + lane];
        accx += xv * w.x; accy += xv * w.y;
    }
    #pragma unroll 16
    for (int k = 0; k < 64; k++) {
        float xv = __shfl(xb, k);
        float2 w = W2[(k + 64) * 64 + lane];
        accx += xv * w.x; accy += xv * w.y;
    }
    float2 o; o.x = accx; o.y = accy;
    ((float2*)(h + (size_t)n * F))[lane] = o;
    float2 as2 = ((const float2*)a_s)[lane];
    float2 ad2 = ((const float2*)a_d)[lane];
    float ps = accx * as2.x + accy * as2.y;
    float pd = accx * ad2.x + accy * ad2.y;
    #pragma unroll
    for (int o2 = 32; o2 > 0; o2 >>= 1) {
        ps += __shfl_xor(ps, o2);
        pd += __shfl_xor(pd, o2);
    }
    if (lane == 0) { hs_src[n] = ps; hs_dst[n] = pd; }
}

// ---------------- per-node GAT aggregation (softmax over in-edges) ----------------
__global__ __launch_bounds__(256) void k_agg(
    const float* __restrict__ h, const int* __restrict__ srcs,
    const int* __restrict__ indptr, const float* __restrict__ hs_src,
    const float* __restrict__ hs_dst, const float* __restrict__ bias,
    float* __restrict__ out, int do_relu) {
    int wave = threadIdx.x >> 6, lane = threadIdx.x & 63;
    int i = blockIdx.x * 4 + wave;
    if (i >= NN) return;
    int p0 = indptr[i], p1 = indptr[i + 1];
    float hd = hs_dst[i];
    // pass 1: max over edges (lane-parallel)
    float m = -1e30f;
    for (int p = p0 + lane; p < p1; p += 64) {
        int s = srcs[p];
        float e = hs_src[s] + hd;
        e = e > 0.f ? e : 0.2f * e;
        m = fmaxf(m, e);
    }
    #pragma unroll
    for (int o = 32; o > 0; o >>= 1) m = fmaxf(m, __shfl_xor(m, o));
    // pass 2: fused denom + weighted sum (uniform scalars broadcast to all lanes)
    float accx = 0.f, accy = 0.f, denom = 0.f;
    for (int p = p0; p < p1; p++) {
        int s = srcs[p];
        float e = hs_src[s] + hd;
        e = e > 0.f ? e : 0.2f * e;
        float ex = __expf(e - m);
        denom += ex;
        float2 hv = ((const float2*)(h + (size_t)s * F))[lane];
        accx += ex * hv.x; accy += ex * hv.y;
    }
    float inv = 1.f / denom;
    float2 b2 = ((const float2*)bias)[lane];
    float ox = accx * inv + b2.x;
    float oy = accy * inv + b2.y;
    if (do_relu) { ox = fmaxf(ox, 0.f); oy = fmaxf(oy, 0.f); }
    float2 o; o.x = ox; o.y = oy;
    ((float2*)(out + (size_t)i * F))[lane] = o;
}

// ---------------- pooling (linearity-fused) + silu + up-proj ----------------
__global__ __launch_bounds__(256) void k_prompt(
    const float* __restrict__ x3, const float* __restrict__ hidden,
    const int* __restrict__ offs, const int* __restrict__ seq_len,
    const float* __restrict__ W_dc, const float* __restrict__ b_dc,
    const float* __restrict__ W_down, const float* __restrict__ b_down,
    const float* __restrict__ W_up, const float* __restrict__ b_up,
    float* __restrict__ out) {
    int b = blockIdx.x >> 5;
    int t = blockIdx.x & 31;
    int tid = threadIdx.x;
    __shared__ float sA[256];
    __shared__ float s128[F];
    __shared__ float s1024[HID];
    __shared__ float sp[DWN];
    int off = offs[b];
    int C = offs[b + 1] - off;
    int sl = seq_len[b];
    int L = C + sl;
    int start = (t * L) / TP;
    int end = ((t + 1) * L + TP - 1) / TP;
    int cnt = end - start;
    int ce = min(end, C);
    int n_ctx = max(ce - start, 0);
    int hs0 = max(start - C, 0);
    int hs1 = max(end - C, 0);
    int n_hs = hs1 - hs0;
    // phase A: ctx row-range sum over x3 (128 cols, 2 row-halves)
    {
        int j = tid & 127, hf = tid >> 7;
        int half = n_ctx >> 1;
        int r0 = start + (hf ? half : 0);
        int r1 = start + (hf ? n_ctx : half);
        float s = 0.f;
        for (int r = r0; r < r1; r++) s += x3[(size_t)(off + r) * F + j];
        sA[tid] = s;
    }
    __syncthreads();
    if (tid < F) s128[tid] = sA[tid] + sA[tid + 128];
    // phase B: hidden row-range sum (1024 cols, 4 per thread)
    {
        float a0 = 0.f, a1 = 0.f, a2 = 0.f, a3 = 0.f;
        const float* hb = hidden + (size_t)b * SEQ * HID;
        for (int r = hs0; r < hs1; r++) {
            const float* row = hb + (size_t)r * HID;
            a0 += row[tid]; a1 += row[tid + 256];
            a2 += row[tid + 512]; a3 += row[tid + 768];
        }
        s1024[tid] = a0; s1024[tid + 256] = a1;
        s1024[tid + 512] = a2; s1024[tid + 768] = a3;
    }
    __syncthreads();
    // phase C: pooled value for DOWN cols, then silu
    {
        float p = (float)n_ctx * b_dc[tid] + (float)n_hs * b_down[tid];
        for (int k = 0; k < F; k++)   p += s128[k] * W_dc[k * DWN + tid];
        for (int k = 0; k < HID; k++) p += s1024[k] * W_down[k * DWN + tid];
        p /= (float)cnt;
        sp[tid] = p / (1.f + __expf(-p));
    }
    __syncthreads();
    // phase D: out = silu(prompt) @ W_up + b_up (4 outputs/thread)
    {
        int o = tid * 4;
        float4 acc = *(const float4*)&b_up[o];
        for (int k = 0; k < DWN; k++) {
            float s = sp[k];
            float4 w = *(const float4*)&W_up[(size_t)k * HID + o];
            acc.x += s * w.x; acc.y += s * w.y; acc.z += s * w.z; acc.w += s * w.w;
        }
        *(float4*)&out[((size_t)(b * TP + t)) * HID + o] = acc;
    }
}

extern "C" void kernel_launch(void* const* d_in, const int* in_sizes, int n_in,
                              void* d_out, int out_size, void* d_ws, size_t ws_size,
                              hipStream_t stream) {
    const int*   graph_x   = (const int*)d_in[0];
    const int*   edge_idx  = (const int*)d_in[1];
    const int*   batch_ids = (const int*)d_in[2];
    const float* hidden    = (const float*)d_in[3];
    const int*   seq_len   = (const int*)d_in[4];
    const float* emb       = (const float*)d_in[5];
    const float* gat_W     = (const float*)d_in[6];
    const float* gat_as    = (const float*)d_in[7];
    const float* gat_ad    = (const float*)d_in[8];
    const float* gat_b     = (const float*)d_in[9];
    const float* W_down    = (const float*)d_in[10];
    const float* b_down    = (const float*)d_in[11];
    const float* W_dc      = (const float*)d_in[12];
    const float* b_dc      = (const float*)d_in[13];
    const float* W_up      = (const float*)d_in[14];
    const float* b_up      = (const float*)d_in[15];
    float* out = (float*)d_out;

    char* ws = (char*)d_ws;
    float* bufA   = (float*)(ws);                   // 51,200,000 B
    float* bufB   = (float*)(ws + 51200000);        // 51,200,000 B
    float* hs_src = (float*)(ws + 102400000);       // 400,000 B
    float* hs_dst = (float*)(ws + 102800000);       // 400,000 B
    int*   counts = (int*)  (ws + 103200000);       // 400,000 B
    int*   indptr = (int*)  (ws + 103600000);       // 400,004 B
    int*   cursor = (int*)  (ws + 104000128);       // 400,000 B
    int*   srcs   = (int*)  (ws + 104400128);       // 3,600,000 B
    int*   bsum   = (int*)  (ws + 108000128);       // 800 B
    int*   boff   = (int*)  (ws + 108001128);       // 804 B
    int*   offs   = (int*)  (ws + 108002128);       // 36 B

    hipMemsetAsync(counts, 0, NN * sizeof(int), stream);
    k_offsets<<<(NN + 255) / 256, 256, 0, stream>>>(batch_ids, offs);
    k_embed<<<NN / 8, 256, 0, stream>>>(graph_x, emb, bufA);
    k_hist<<<(E2 + 255) / 256, 256, 0, stream>>>(edge_idx, counts);
    k_bsum<<<200, 256, 0, stream>>>(counts, bsum);
    k_boff<<<1, 64, 0, stream>>>(bsum, boff);
    k_indptr<<<200, 64, 0, stream>>>(counts, boff, indptr, cursor);
    k_scatter<<<(E2 + 255) / 256, 256, 0, stream>>>(edge_idx, cursor, srcs);

    for (int l = 0; l < 3; l++) {
        k_gemm<<<NN / 4, 256, 0, stream>>>(bufA, gat_W + l * F * F, gat_as + l * F,
                                           gat_ad + l * F, bufB, hs_src, hs_dst);
        k_agg<<<NN / 4, 256, 0, stream>>>(bufB, srcs, indptr, hs_src, hs_dst,
                                          gat_b + l * F, bufA, (l < 2) ? 1 : 0);
    }
    k_prompt<<<NB * TP, 256, 0, stream>>>(bufA, hidden, offs, seq_len,
                                          W_dc, b_dc, W_down, b_down, W_up, b_up, out);
}

// Round 2
// 762.007 us; speedup vs baseline: 2.1958x; 2.1958x over previous
//
#include <hip/hip_runtime.h>
#include <hip/hip_bf16.h>

#define NN 100000   // nodes
#define NE 800000   // edges (without self loops)
#define E2 900000   // edges + self loops
#define F  128      // KGE
#define NB 8        // batch
#define SEQ 1024
#define HID 1024
#define DWN 256
#define TP 32

// ---------------- batch offsets from sorted batch_ids ----------------
__global__ void k_offsets(const int* __restrict__ bids, int* __restrict__ offs) {
    int n = blockIdx.x * 256 + threadIdx.x;
    if (n >= NN) return;
    int b = bids[n];
    if (n == 0) offs[0] = 0;
    else if (bids[n - 1] != b) offs[b] = n;
    if (n == NN - 1) offs[b + 1] = NN;
}

// ---------------- embedding gather: x[n] = emb[graph_x[n]] ----------------
__global__ void k_embed(const int* __restrict__ gx, const float* __restrict__ emb,
                        float* __restrict__ x) {
    int i = blockIdx.x * 256 + threadIdx.x;   // over NN*32 float4 chunks
    int n = i >> 5, c = i & 31;
    float4 v = ((const float4*)(emb + (size_t)gx[n] * F))[c];
    ((float4*)(x + (size_t)n * F))[c] = v;
}

// ---------------- CSR build ----------------
__global__ void k_hist(const int* __restrict__ ei, int* __restrict__ counts) {
    int e = blockIdx.x * 256 + threadIdx.x;
    if (e >= E2) return;
    int dst = (e < NE) ? ei[NE + e] : (e - NE);
    atomicAdd(&counts[dst], 1);
}

__global__ void k_bsum(const int* __restrict__ counts, int* __restrict__ bsum) {
    __shared__ int red[256];
    int b = blockIdx.x, t = threadIdx.x;
    int base = b * 500;
    int s = 0;
    for (int i = t; i < 500; i += 256) s += counts[base + i];
    red[t] = s; __syncthreads();
    for (int o = 128; o > 0; o >>= 1) { if (t < o) red[t] += red[t + o]; __syncthreads(); }
    if (t == 0) bsum[b] = red[0];
}

__global__ void k_boff(const int* __restrict__ bsum, int* __restrict__ boff) {
    if (threadIdx.x == 0) {
        int r = 0;
        for (int i = 0; i < 200; i++) { boff[i] = r; r += bsum[i]; }
        boff[200] = r;
    }
}

__global__ void k_indptr(const int* __restrict__ counts, const int* __restrict__ boff,
                         int* __restrict__ indptr, int* __restrict__ cursor) {
    int b = blockIdx.x;
    if (threadIdx.x != 0) return;
    int r = boff[b];
    int base = b * 500;
    for (int i = 0; i < 500; i++) {
        int gi = base + i;
        indptr[gi] = r; cursor[gi] = r;
        r += counts[gi];
    }
    if (b == 199) indptr[NN] = r;
}

__global__ void k_scatter(const int* __restrict__ ei, int* __restrict__ cursor,
                          int* __restrict__ srcs) {
    int e = blockIdx.x * 256 + threadIdx.x;
    if (e >= E2) return;
    int src, dst;
    if (e < NE) { src = ei[e]; dst = ei[NE + e]; }
    else        { src = dst = e - NE; }
    int pos = atomicAdd(&cursor[dst], 1);
    srcs[pos] = src;
}

// ---------------- tiled GEMM: h = x @ W, fused hs_src/hs_dst epilogue ----------
// BM=128 rows/block, BK=32, 256 threads (16x16), 8x8 acc per thread.
// Thread (ty,tx): rows ty*8..ty*8+7, cols {tx*4..tx*4+3} U {64+tx*4..64+tx*4+3}.
__global__ __launch_bounds__(256) void k_gemm(
    const float* __restrict__ x, const float* __restrict__ W,
    const float* __restrict__ a_s, const float* __restrict__ a_d,
    float* __restrict__ h, float* __restrict__ hs_src, float* __restrict__ hs_dst) {
    __shared__ float At[32][132];   // [k][row] transposed A tile (132: keep 16B-aligned rows)
    __shared__ float Ws[32][132];   // [k][col]
    const int tid = threadIdx.x;
    const int ty = tid >> 4, tx = tid & 15;
    const int row0 = blockIdx.x * 128;

    float acc[8][8];
    #pragma unroll
    for (int i = 0; i < 8; i++)
        #pragma unroll
        for (int j = 0; j < 8; j++) acc[i][j] = 0.f;

    const int lr = tid >> 3;      // 0..31
    const int lc = tid & 7;       // float4 slot in 32-float k-slice
    const int wr = tid >> 5;      // 0..7
    const int wc = tid & 31;      // float4 slot in 128-col row

    for (int kt = 0; kt < 4; kt++) {
        #pragma unroll
        for (int p = 0; p < 4; p++) {
            int r = lr + 32 * p;
            int rg = row0 + r; if (rg > NN - 1) rg = NN - 1;
            float4 v = *(const float4*)&x[(size_t)rg * F + kt * 32 + lc * 4];
            At[lc * 4 + 0][r] = v.x;
            At[lc * 4 + 1][r] = v.y;
            At[lc * 4 + 2][r] = v.z;
            At[lc * 4 + 3][r] = v.w;
        }
        #pragma unroll
        for (int p = 0; p < 4; p++) {
            int k = wr + 8 * p;
            float4 v = *(const float4*)&W[(size_t)(kt * 32 + k) * F + wc * 4];
            *(float4*)&Ws[k][wc * 4] = v;
        }
        __syncthreads();
        #pragma unroll 8
        for (int k = 0; k < 32; k++) {
            float4 a0 = *(const float4*)&At[k][ty * 8];
            float4 a1 = *(const float4*)&At[k][ty * 8 + 4];
            float4 w0 = *(const float4*)&Ws[k][tx * 4];
            float4 w1 = *(const float4*)&Ws[k][64 + tx * 4];
            float av[8] = {a0.x, a0.y, a0.z, a0.w, a1.x, a1.y, a1.z, a1.w};
            float wv[8] = {w0.x, w0.y, w0.z, w0.w, w1.x, w1.y, w1.z, w1.w};
            #pragma unroll
            for (int i = 0; i < 8; i++)
                #pragma unroll
                for (int j = 0; j < 8; j++)
                    acc[i][j] += av[i] * wv[j];
        }
        __syncthreads();
    }

    float4 as0 = *(const float4*)&a_s[tx * 4];
    float4 as1 = *(const float4*)&a_s[64 + tx * 4];
    float4 ad0 = *(const float4*)&a_d[tx * 4];
    float4 ad1 = *(const float4*)&a_d[64 + tx * 4];
    float asv[8] = {as0.x, as0.y, as0.z, as0.w, as1.x, as1.y, as1.z, as1.w};
    float adv[8] = {ad0.x, ad0.y, ad0.z, ad0.w, ad1.x, ad1.y, ad1.z, ad1.w};

    #pragma unroll
    for (int i = 0; i < 8; i++) {
        int rg = row0 + ty * 8 + i;
        bool ok = rg < NN;
        if (ok) {
            float4 o0, o1;
            o0.x = acc[i][0]; o0.y = acc[i][1]; o0.z = acc[i][2]; o0.w = acc[i][3];
            o1.x = acc[i][4]; o1.y = acc[i][5]; o1.z = acc[i][6]; o1.w = acc[i][7];
            *(float4*)&h[(size_t)rg * F + tx * 4] = o0;
            *(float4*)&h[(size_t)rg * F + 64 + tx * 4] = o1;
        }
        float ps = 0.f, pd = 0.f;
        #pragma unroll
        for (int j = 0; j < 8; j++) { ps += acc[i][j] * asv[j]; pd += acc[i][j] * adv[j]; }
        #pragma unroll
        for (int m = 8; m >= 1; m >>= 1) { ps += __shfl_xor(ps, m); pd += __shfl_xor(pd, m); }
        if (ok && tx == 0) { hs_src[rg] = ps; hs_dst[rg] = pd; }
    }
}

// ---------------- per-node GAT aggregation (softmax over in-edges) ----------------
__global__ __launch_bounds__(256) void k_agg(
    const float* __restrict__ h, const int* __restrict__ srcs,
    const int* __restrict__ indptr, const float* __restrict__ hs_src,
    const float* __restrict__ hs_dst, const float* __restrict__ bias,
    float* __restrict__ out, int do_relu) {
    int wave = threadIdx.x >> 6, lane = threadIdx.x & 63;
    int i = blockIdx.x * 4 + wave;
    if (i >= NN) return;
    int p0 = indptr[i], p1 = indptr[i + 1];
    float hd = hs_dst[i];
    // pass 1: max over edges (lane-parallel)
    float m = -1e30f;
    for (int p = p0 + lane; p < p1; p += 64) {
        int s = srcs[p];
        float e = hs_src[s] + hd;
        e = e > 0.f ? e : 0.2f * e;
        m = fmaxf(m, e);
    }
    #pragma unroll
    for (int o = 32; o > 0; o >>= 1) m = fmaxf(m, __shfl_xor(m, o));
    // pass 2: fused denom + weighted sum (uniform scalars broadcast to all lanes)
    float accx = 0.f, accy = 0.f, denom = 0.f;
    for (int p = p0; p < p1; p++) {
        int s = srcs[p];
        float e = hs_src[s] + hd;
        e = e > 0.f ? e : 0.2f * e;
        float ex = __expf(e - m);
        denom += ex;
        float2 hv = ((const float2*)(h + (size_t)s * F))[lane];
        accx += ex * hv.x; accy += ex * hv.y;
    }
    float inv = 1.f / denom;
    float2 b2 = ((const float2*)bias)[lane];
    float ox = accx * inv + b2.x;
    float oy = accy * inv + b2.y;
    if (do_relu) { ox = fmaxf(ox, 0.f); oy = fmaxf(oy, 0.f); }
    float2 o; o.x = ox; o.y = oy;
    ((float2*)(out + (size_t)i * F))[lane] = o;
}

// ---------------- pooling (linearity-fused) + silu + up-proj ----------------
__global__ __launch_bounds__(256) void k_prompt(
    const float* __restrict__ x3, const float* __restrict__ hidden,
    const int* __restrict__ offs, const int* __restrict__ seq_len,
    const float* __restrict__ W_dc, const float* __restrict__ b_dc,
    const float* __restrict__ W_down, const float* __restrict__ b_down,
    const float* __restrict__ W_up, const float* __restrict__ b_up,
    float* __restrict__ out) {
    int b = blockIdx.x >> 5;
    int t = blockIdx.x & 31;
    int tid = threadIdx.x;
    __shared__ float sA[256];
    __shared__ float s128[F];
    __shared__ float s1024[HID];
    __shared__ float sp[DWN];
    int off = offs[b];
    int C = offs[b + 1] - off;
    int sl = seq_len[b];
    int L = C + sl;
    int start = (t * L) / TP;
    int end = ((t + 1) * L + TP - 1) / TP;
    int cnt = end - start;
    int ce = min(end, C);
    int n_ctx = max(ce - start, 0);
    int hs0 = max(start - C, 0);
    int hs1 = max(end - C, 0);
    int n_hs = hs1 - hs0;
    // phase A: ctx row-range sum over x3 (128 cols, 2 row-halves)
    {
        int j = tid & 127, hf = tid >> 7;
        int half = n_ctx >> 1;
        int r0 = start + (hf ? half : 0);
        int r1 = start + (hf ? n_ctx : half);
        float s = 0.f;
        for (int r = r0; r < r1; r++) s += x3[(size_t)(off + r) * F + j];
        sA[tid] = s;
    }
    __syncthreads();
    if (tid < F) s128[tid] = sA[tid] + sA[tid + 128];
    // phase B: hidden row-range sum (1024 cols, 4 per thread)
    {
        float a0 = 0.f, a1 = 0.f, a2 = 0.f, a3 = 0.f;
        const float* hb = hidden + (size_t)b * SEQ * HID;
        for (int r = hs0; r < hs1; r++) {
            const float* row = hb + (size_t)r * HID;
            a0 += row[tid]; a1 += row[tid + 256];
            a2 += row[tid + 512]; a3 += row[tid + 768];
        }
        s1024[tid] = a0; s1024[tid + 256] = a1;
        s1024[tid + 512] = a2; s1024[tid + 768] = a3;
    }
    __syncthreads();
    // phase C: pooled value for DOWN cols, then silu
    {
        float p = (float)n_ctx * b_dc[tid] + (float)n_hs * b_down[tid];
        for (int k = 0; k < F; k++)   p += s128[k] * W_dc[k * DWN + tid];
        for (int k = 0; k < HID; k++) p += s1024[k] * W_down[k * DWN + tid];
        p /= (float)cnt;
        sp[tid] = p / (1.f + __expf(-p));
    }
    __syncthreads();
    // phase D: out = silu(prompt) @ W_up + b_up (4 outputs/thread)
    {
        int o = tid * 4;
        float4 acc = *(const float4*)&b_up[o];
        for (int k = 0; k < DWN; k++) {
            float s = sp[k];
            float4 w = *(const float4*)&W_up[(size_t)k * HID + o];
            acc.x += s * w.x; acc.y += s * w.y; acc.z += s * w.z; acc.w += s * w.w;
        }
        *(float4*)&out[((size_t)(b * TP + t)) * HID + o] = acc;
    }
}

extern "C" void kernel_launch(void* const* d_in, const int* in_sizes, int n_in,
                              void* d_out, int out_size, void* d_ws, size_t ws_size,
                              hipStream_t stream) {
    const int*   graph_x   = (const int*)d_in[0];
    const int*   edge_idx  = (const int*)d_in[1];
    const int*   batch_ids = (const int*)d_in[2];
    const float* hidden    = (const float*)d_in[3];
    const int*   seq_len   = (const int*)d_in[4];
    const float* emb       = (const float*)d_in[5];
    const float* gat_W     = (const float*)d_in[6];
    const float* gat_as    = (const float*)d_in[7];
    const float* gat_ad    = (const float*)d_in[8];
    const float* gat_b     = (const float*)d_in[9];
    const float* W_down    = (const float*)d_in[10];
    const float* b_down    = (const float*)d_in[11];
    const float* W_dc      = (const float*)d_in[12];
    const float* b_dc      = (const float*)d_in[13];
    const float* W_up      = (const float*)d_in[14];
    const float* b_up      = (const float*)d_in[15];
    float* out = (float*)d_out;

    char* ws = (char*)d_ws;
    float* bufA   = (float*)(ws);                   // 51,200,000 B
    float* bufB   = (float*)(ws + 51200000);        // 51,200,000 B
    float* hs_src = (float*)(ws + 102400000);       // 400,000 B
    float* hs_dst = (float*)(ws + 102800000);       // 400,000 B
    int*   counts = (int*)  (ws + 103200000);       // 400,000 B
    int*   indptr = (int*)  (ws + 103600000);       // 400,004 B
    int*   cursor = (int*)  (ws + 104000128);       // 400,000 B
    int*   srcs   = (int*)  (ws + 104400128);       // 3,600,000 B
    int*   bsum   = (int*)  (ws + 108000128);       // 800 B
    int*   boff   = (int*)  (ws + 108001128);       // 804 B
    int*   offs   = (int*)  (ws + 108002128);       // 36 B

    hipMemsetAsync(counts, 0, NN * sizeof(int), stream);
    k_offsets<<<(NN + 255) / 256, 256, 0, stream>>>(batch_ids, offs);
    k_embed<<<NN / 8, 256, 0, stream>>>(graph_x, emb, bufA);
    k_hist<<<(E2 + 255) / 256, 256, 0, stream>>>(edge_idx, counts);
    k_bsum<<<200, 256, 0, stream>>>(counts, bsum);
    k_boff<<<1, 64, 0, stream>>>(bsum, boff);
    k_indptr<<<200, 64, 0, stream>>>(counts, boff, indptr, cursor);
    k_scatter<<<(E2 + 255) / 256, 256, 0, stream>>>(edge_idx, cursor, srcs);

    for (int l = 0; l < 3; l++) {
        k_gemm<<<(NN + 127) / 128, 256, 0, stream>>>(bufA, gat_W + l * F * F, gat_as + l * F,
                                                     gat_ad + l * F, bufB, hs_src, hs_dst);
        k_agg<<<(NN + 3) / 4, 256, 0, stream>>>(bufB, srcs, indptr, hs_src, hs_dst,
                                                gat_b + l * F, bufA, (l < 2) ? 1 : 0);
    }
    k_prompt<<<NB * TP, 256, 0, stream>>>(bufA, hidden, offs, seq_len,
                                          W_dc, b_dc, W_down, b_down, W_up, b_up, out);
}

// Round 3
// 648.427 us; speedup vs baseline: 2.5804x; 1.1752x over previous
//
#include <hip/hip_runtime.h>
#include <hip/hip_bf16.h>

#define NN 100000   // nodes
#define NE 800000   // edges (without self loops)
#define E2 900000   // edges + self loops
#define F  128      // KGE
#define NB 8        // batch
#define SEQ 1024
#define HID 1024
#define DWN 256
#define TP 32

// ---------------- batch offsets from sorted batch_ids ----------------
__global__ void k_offsets(const int* __restrict__ bids, int* __restrict__ offs) {
    int n = blockIdx.x * 256 + threadIdx.x;
    if (n >= NN) return;
    int b = bids[n];
    if (n == 0) offs[0] = 0;
    else if (bids[n - 1] != b) offs[b] = n;
    if (n == NN - 1) offs[b + 1] = NN;
}

// ---------------- embedding gather: x[n] = emb[graph_x[n]] ----------------
__global__ void k_embed(const int* __restrict__ gx, const float* __restrict__ emb,
                        float* __restrict__ x) {
    int i = blockIdx.x * 256 + threadIdx.x;   // over NN*32 float4 chunks
    int n = i >> 5, c = i & 31;
    float4 v = ((const float4*)(emb + (size_t)gx[n] * F))[c];
    ((float4*)(x + (size_t)n * F))[c] = v;
}

// ---------------- CSR build ----------------
__global__ void k_hist(const int* __restrict__ ei, int* __restrict__ counts) {
    int e = blockIdx.x * 256 + threadIdx.x;
    if (e >= E2) return;
    int dst = (e < NE) ? ei[NE + e] : (e - NE);
    atomicAdd(&counts[dst], 1);
}

__global__ void k_bsum(const int* __restrict__ counts, int* __restrict__ bsum) {
    __shared__ int red[256];
    int b = blockIdx.x, t = threadIdx.x;
    int base = b * 500;
    int s = 0;
    for (int i = t; i < 500; i += 256) s += counts[base + i];
    red[t] = s; __syncthreads();
    for (int o = 128; o > 0; o >>= 1) { if (t < o) red[t] += red[t + o]; __syncthreads(); }
    if (t == 0) bsum[b] = red[0];
}

__global__ void k_boff(const int* __restrict__ bsum, int* __restrict__ boff) {
    if (threadIdx.x == 0) {
        int r = 0;
        for (int i = 0; i < 200; i++) { boff[i] = r; r += bsum[i]; }
        boff[200] = r;
    }
}

__global__ void k_indptr(const int* __restrict__ counts, const int* __restrict__ boff,
                         int* __restrict__ indptr, int* __restrict__ cursor) {
    int b = blockIdx.x;
    if (threadIdx.x != 0) return;
    int r = boff[b];
    int base = b * 500;
    for (int i = 0; i < 500; i++) {
        int gi = base + i;
        indptr[gi] = r; cursor[gi] = r;
        r += counts[gi];
    }
    if (b == 199) indptr[NN] = r;
}

__global__ void k_scatter(const int* __restrict__ ei, int* __restrict__ cursor,
                          int* __restrict__ srcs) {
    int e = blockIdx.x * 256 + threadIdx.x;
    if (e >= E2) return;
    int src, dst;
    if (e < NE) { src = ei[e]; dst = ei[NE + e]; }
    else        { src = dst = e - NE; }
    int pos = atomicAdd(&cursor[dst], 1);
    srcs[pos] = src;
}

// ---------------- tiled GEMM: h = x @ W, fused hs_src/hs_dst epilogue ----------
__global__ __launch_bounds__(256) void k_gemm(
    const float* __restrict__ x, const float* __restrict__ W,
    const float* __restrict__ a_s, const float* __restrict__ a_d,
    float* __restrict__ h, float* __restrict__ hs_src, float* __restrict__ hs_dst) {
    __shared__ float At[32][132];
    __shared__ float Ws[32][132];
    const int tid = threadIdx.x;
    const int ty = tid >> 4, tx = tid & 15;
    const int row0 = blockIdx.x * 128;

    float acc[8][8];
    #pragma unroll
    for (int i = 0; i < 8; i++)
        #pragma unroll
        for (int j = 0; j < 8; j++) acc[i][j] = 0.f;

    const int lr = tid >> 3;
    const int lc = tid & 7;
    const int wr = tid >> 5;
    const int wc = tid & 31;

    for (int kt = 0; kt < 4; kt++) {
        #pragma unroll
        for (int p = 0; p < 4; p++) {
            int r = lr + 32 * p;
            int rg = row0 + r; if (rg > NN - 1) rg = NN - 1;
            float4 v = *(const float4*)&x[(size_t)rg * F + kt * 32 + lc * 4];
            At[lc * 4 + 0][r] = v.x;
            At[lc * 4 + 1][r] = v.y;
            At[lc * 4 + 2][r] = v.z;
            At[lc * 4 + 3][r] = v.w;
        }
        #pragma unroll
        for (int p = 0; p < 4; p++) {
            int k = wr + 8 * p;
            float4 v = *(const float4*)&W[(size_t)(kt * 32 + k) * F + wc * 4];
            *(float4*)&Ws[k][wc * 4] = v;
        }
        __syncthreads();
        #pragma unroll 8
        for (int k = 0; k < 32; k++) {
            float4 a0 = *(const float4*)&At[k][ty * 8];
            float4 a1 = *(const float4*)&At[k][ty * 8 + 4];
            float4 w0 = *(const float4*)&Ws[k][tx * 4];
            float4 w1 = *(const float4*)&Ws[k][64 + tx * 4];
            float av[8] = {a0.x, a0.y, a0.z, a0.w, a1.x, a1.y, a1.z, a1.w};
            float wv[8] = {w0.x, w0.y, w0.z, w0.w, w1.x, w1.y, w1.z, w1.w};
            #pragma unroll
            for (int i = 0; i < 8; i++)
                #pragma unroll
                for (int j = 0; j < 8; j++)
                    acc[i][j] += av[i] * wv[j];
        }
        __syncthreads();
    }

    float4 as0 = *(const float4*)&a_s[tx * 4];
    float4 as1 = *(const float4*)&a_s[64 + tx * 4];
    float4 ad0 = *(const float4*)&a_d[tx * 4];
    float4 ad1 = *(const float4*)&a_d[64 + tx * 4];
    float asv[8] = {as0.x, as0.y, as0.z, as0.w, as1.x, as1.y, as1.z, as1.w};
    float adv[8] = {ad0.x, ad0.y, ad0.z, ad0.w, ad1.x, ad1.y, ad1.z, ad1.w};

    #pragma unroll
    for (int i = 0; i < 8; i++) {
        int rg = row0 + ty * 8 + i;
        bool ok = rg < NN;
        if (ok) {
            float4 o0, o1;
            o0.x = acc[i][0]; o0.y = acc[i][1]; o0.z = acc[i][2]; o0.w = acc[i][3];
            o1.x = acc[i][4]; o1.y = acc[i][5]; o1.z = acc[i][6]; o1.w = acc[i][7];
            *(float4*)&h[(size_t)rg * F + tx * 4] = o0;
            *(float4*)&h[(size_t)rg * F + 64 + tx * 4] = o1;
        }
        float ps = 0.f, pd = 0.f;
        #pragma unroll
        for (int j = 0; j < 8; j++) { ps += acc[i][j] * asv[j]; pd += acc[i][j] * adv[j]; }
        #pragma unroll
        for (int m = 8; m >= 1; m >>= 1) { ps += __shfl_xor(ps, m); pd += __shfl_xor(pd, m); }
        if (ok && tx == 0) { hs_src[rg] = ps; hs_dst[rg] = pd; }
    }
}

// ---------------- per-node GAT aggregation (softmax over in-edges) ----------------
// Pass 2 pipelined: per 64-edge chunk, load ids + exp lane-parallel, then
// broadcast via shfl so the h-row gathers are independent in-flight loads.
__global__ __launch_bounds__(256) void k_agg(
    const float* __restrict__ h, const int* __restrict__ srcs,
    const int* __restrict__ indptr, const float* __restrict__ hs_src,
    const float* __restrict__ hs_dst, const float* __restrict__ bias,
    float* __restrict__ out, int do_relu) {
    int wave = threadIdx.x >> 6, lane = threadIdx.x & 63;
    int i = blockIdx.x * 4 + wave;
    if (i >= NN) return;
    int p0 = indptr[i], p1 = indptr[i + 1];
    float hd = hs_dst[i];
    // pass 1: max over edges (lane-parallel)
    float m = -1e30f;
    for (int p = p0 + lane; p < p1; p += 64) {
        int s = srcs[p];
        float e = hs_src[s] + hd;
        e = e > 0.f ? e : 0.2f * e;
        m = fmaxf(m, e);
    }
    #pragma unroll
    for (int o = 32; o > 0; o >>= 1) m = fmaxf(m, __shfl_xor(m, o));
    // pass 2: chunked, shfl-broadcast
    float accx = 0.f, accy = 0.f, dl = 0.f;
    for (int base = p0; base < p1; base += 64) {
        int cn = min(64, p1 - base);
        int s = 0; float ex = 0.f;
        if (lane < cn) {
            s = srcs[base + lane];
            float e = hs_src[s] + hd;
            e = e > 0.f ? e : 0.2f * e;
            ex = __expf(e - m);
        }
        dl += ex;
        for (int j = 0; j < cn; j++) {
            float exj = __shfl(ex, j);
            int sj = __shfl(s, j);
            float2 hv = ((const float2*)(h + (size_t)sj * F))[lane];
            accx += exj * hv.x; accy += exj * hv.y;
        }
    }
    #pragma unroll
    for (int o = 32; o > 0; o >>= 1) dl += __shfl_xor(dl, o);
    float inv = 1.f / dl;
    float2 b2 = ((const float2*)bias)[lane];
    float ox = accx * inv + b2.x;
    float oy = accy * inv + b2.y;
    if (do_relu) { ox = fmaxf(ox, 0.f); oy = fmaxf(oy, 0.f); }
    float2 o; o.x = ox; o.y = oy;
    ((float2*)(out + (size_t)i * F))[lane] = o;
}

// ---------------- bin sums: ctx rows (x3, 128 cols) ----------------
// wave = 64-row chunk; lane holds col pair; register-accumulate per bin,
// atomic flush on bin change. Boundary rows (t_max>t_min) add directly.
__global__ __launch_bounds__(256) void k_binsum_ctx(
    const float* __restrict__ x3, const int* __restrict__ bids,
    const int* __restrict__ offs, const int* __restrict__ seq_len,
    float* __restrict__ s128) {
    int wid = blockIdx.x * 4 + (threadIdx.x >> 6);
    int lane = threadIdx.x & 63;
    int r0 = wid * 64;
    if (r0 >= NN) return;
    int r1 = min(r0 + 64, NN);
    float ax = 0.f, ay = 0.f;
    int cur = -1;
    int cb = -1, off = 0, C = 0, L = 1;
    for (int r = r0; r < r1; r++) {
        int b = bids[r];
        if (b != cb) { cb = b; off = offs[b]; C = offs[b + 1] - off; L = C + seq_len[b]; }
        int q = r - off;
        int tmin = (q * TP) / L;
        int tmax = ((q + 1) * TP - 1) / L;
        float2 v = ((const float2*)(x3 + (size_t)r * F))[lane];
        int bin = b * TP + tmin;
        if (bin != cur) {
            if (cur >= 0) {
                atomicAdd(&s128[(size_t)cur * F + 2 * lane], ax);
                atomicAdd(&s128[(size_t)cur * F + 2 * lane + 1], ay);
            }
            cur = bin; ax = 0.f; ay = 0.f;
        }
        ax += v.x; ay += v.y;
        if (tmax != tmin) {
            atomicAdd(&s128[(size_t)(b * TP + tmax) * F + 2 * lane], v.x);
            atomicAdd(&s128[(size_t)(b * TP + tmax) * F + 2 * lane + 1], v.y);
        }
    }
    if (cur >= 0) {
        atomicAdd(&s128[(size_t)cur * F + 2 * lane], ax);
        atomicAdd(&s128[(size_t)cur * F + 2 * lane + 1], ay);
    }
}

// ---------------- bin sums: hidden rows (1024 cols) ----------------
// wave = 16-row chunk within one batch; 16 f32 accumulators per lane.
__global__ __launch_bounds__(256) void k_binsum_hid(
    const float* __restrict__ hidden, const int* __restrict__ offs,
    const int* __restrict__ seq_len, float* __restrict__ s1024) {
    int wid = blockIdx.x * 4 + (threadIdx.x >> 6);   // 0..511
    int lane = threadIdx.x & 63;
    int b = wid >> 6;          // 64 chunks per batch
    int chunk = wid & 63;
    int sl = seq_len[b];
    int r0 = chunk * 16;
    if (r0 >= sl) return;
    int r1 = min(r0 + 16, sl);
    int C = offs[b + 1] - offs[b];
    int L = C + sl;
    float a[16];
    #pragma unroll
    for (int c = 0; c < 16; c++) a[c] = 0.f;
    int cur = -1;
    const float* hb = hidden + (size_t)b * SEQ * HID;
    for (int r = r0; r < r1; r++) {
        int q = C + r;
        int tmin = (q * TP) / L;
        int tmax = ((q + 1) * TP - 1) / L;
        const float4* row = (const float4*)(hb + (size_t)r * HID);
        float4 v0 = row[lane], v1 = row[64 + lane], v2 = row[128 + lane], v3 = row[192 + lane];
        int bin = b * TP + tmin;
        if (bin != cur) {
            if (cur >= 0) {
                float* dst = s1024 + (size_t)cur * HID;
                #pragma unroll
                for (int c = 0; c < 4; c++) atomicAdd(&dst[4 * lane + c], a[c]);
                #pragma unroll
                for (int c = 0; c < 4; c++) atomicAdd(&dst[256 + 4 * lane + c], a[4 + c]);
                #pragma unroll
                for (int c = 0; c < 4; c++) atomicAdd(&dst[512 + 4 * lane + c], a[8 + c]);
                #pragma unroll
                for (int c = 0; c < 4; c++) atomicAdd(&dst[768 + 4 * lane + c], a[12 + c]);
            }
            cur = bin;
            #pragma unroll
            for (int c = 0; c < 16; c++) a[c] = 0.f;
        }
        a[0] += v0.x; a[1] += v0.y; a[2] += v0.z; a[3] += v0.w;
        a[4] += v1.x; a[5] += v1.y; a[6] += v1.z; a[7] += v1.w;
        a[8] += v2.x; a[9] += v2.y; a[10] += v2.z; a[11] += v2.w;
        a[12] += v3.x; a[13] += v3.y; a[14] += v3.z; a[15] += v3.w;
        if (tmax != tmin) {
            float* dst = s1024 + (size_t)(b * TP + tmax) * HID;
            atomicAdd(&dst[4 * lane + 0], v0.x); atomicAdd(&dst[4 * lane + 1], v0.y);
            atomicAdd(&dst[4 * lane + 2], v0.z); atomicAdd(&dst[4 * lane + 3], v0.w);
            atomicAdd(&dst[256 + 4 * lane + 0], v1.x); atomicAdd(&dst[256 + 4 * lane + 1], v1.y);
            atomicAdd(&dst[256 + 4 * lane + 2], v1.z); atomicAdd(&dst[256 + 4 * lane + 3], v1.w);
            atomicAdd(&dst[512 + 4 * lane + 0], v2.x); atomicAdd(&dst[512 + 4 * lane + 1], v2.y);
            atomicAdd(&dst[512 + 4 * lane + 2], v2.z); atomicAdd(&dst[512 + 4 * lane + 3], v2.w);
            atomicAdd(&dst[768 + 4 * lane + 0], v3.x); atomicAdd(&dst[768 + 4 * lane + 1], v3.y);
            atomicAdd(&dst[768 + 4 * lane + 2], v3.z); atomicAdd(&dst[768 + 4 * lane + 3], v3.w);
        }
    }
    if (cur >= 0) {
        float* dst = s1024 + (size_t)cur * HID;
        #pragma unroll
        for (int c = 0; c < 4; c++) atomicAdd(&dst[4 * lane + c], a[c]);
        #pragma unroll
        for (int c = 0; c < 4; c++) atomicAdd(&dst[256 + 4 * lane + c], a[4 + c]);
        #pragma unroll
        for (int c = 0; c < 4; c++) atomicAdd(&dst[512 + 4 * lane + c], a[8 + c]);
        #pragma unroll
        for (int c = 0; c < 4; c++) atomicAdd(&dst[768 + 4 * lane + c], a[12 + c]);
    }
}

// ---------------- final: pooled -> silu -> up-proj ----------------
__global__ __launch_bounds__(256) void k_pool(
    const float* __restrict__ s128, const float* __restrict__ s1024,
    const int* __restrict__ offs, const int* __restrict__ seq_len,
    const float* __restrict__ W_dc, const float* __restrict__ b_dc,
    const float* __restrict__ W_down, const float* __restrict__ b_down,
    const float* __restrict__ W_up, const float* __restrict__ b_up,
    float* __restrict__ out) {
    int b = blockIdx.x >> 5;
    int t = blockIdx.x & 31;
    int tid = threadIdx.x;
    int bin = blockIdx.x;
    __shared__ float sh128[F];
    __shared__ float sh1024[HID];
    __shared__ float sp[DWN];
    int C = offs[b + 1] - offs[b];
    int sl = seq_len[b];
    int L = C + sl;
    int start = (t * L) / TP;
    int end = ((t + 1) * L + TP - 1) / TP;
    int cnt = end - start;
    int ce = min(end, C);
    int n_ctx = max(ce - start, 0);
    int n_hs = max(end - C, 0) - max(start - C, 0);
    if (tid < F) sh128[tid] = s128[(size_t)bin * F + tid];
    #pragma unroll
    for (int c = 0; c < 4; c++) sh1024[tid + 256 * c] = s1024[(size_t)bin * HID + tid + 256 * c];
    __syncthreads();
    {
        float p = (float)n_ctx * b_dc[tid] + (float)n_hs * b_down[tid];
        for (int k = 0; k < F; k++)   p += sh128[k] * W_dc[k * DWN + tid];
        for (int k = 0; k < HID; k++) p += sh1024[k] * W_down[k * DWN + tid];
        p /= (float)cnt;
        sp[tid] = p / (1.f + __expf(-p));
    }
    __syncthreads();
    {
        int o = tid * 4;
        float4 acc = *(const float4*)&b_up[o];
        for (int k = 0; k < DWN; k++) {
            float s = sp[k];
            float4 w = *(const float4*)&W_up[(size_t)k * HID + o];
            acc.x += s * w.x; acc.y += s * w.y; acc.z += s * w.z; acc.w += s * w.w;
        }
        *(float4*)&out[((size_t)(b * TP + t)) * HID + o] = acc;
    }
}

extern "C" void kernel_launch(void* const* d_in, const int* in_sizes, int n_in,
                              void* d_out, int out_size, void* d_ws, size_t ws_size,
                              hipStream_t stream) {
    const int*   graph_x   = (const int*)d_in[0];
    const int*   edge_idx  = (const int*)d_in[1];
    const int*   batch_ids = (const int*)d_in[2];
    const float* hidden    = (const float*)d_in[3];
    const int*   seq_len   = (const int*)d_in[4];
    const float* emb       = (const float*)d_in[5];
    const float* gat_W     = (const float*)d_in[6];
    const float* gat_as    = (const float*)d_in[7];
    const float* gat_ad    = (const float*)d_in[8];
    const float* gat_b     = (const float*)d_in[9];
    const float* W_down    = (const float*)d_in[10];
    const float* b_down    = (const float*)d_in[11];
    const float* W_dc      = (const float*)d_in[12];
    const float* b_dc      = (const float*)d_in[13];
    const float* W_up      = (const float*)d_in[14];
    const float* b_up      = (const float*)d_in[15];
    float* out = (float*)d_out;

    char* ws = (char*)d_ws;
    float* bufA   = (float*)(ws);                   // 51,200,000 B
    float* bufB   = (float*)(ws + 51200000);        // 51,200,000 B
    float* hs_src = (float*)(ws + 102400000);
    float* hs_dst = (float*)(ws + 102800000);
    int*   counts = (int*)  (ws + 103200000);
    int*   indptr = (int*)  (ws + 103600000);
    int*   cursor = (int*)  (ws + 104000128);
    int*   srcs   = (int*)  (ws + 104400128);
    int*   bsum   = (int*)  (ws + 108000128);
    int*   boff   = (int*)  (ws + 108001128);
    int*   offs   = (int*)  (ws + 108002128);
    // bin tables overlay bufB (h is dead after last k_agg)
    float* s128   = bufB;                    // 256*128*4  = 131,072 B
    float* s1024  = bufB + 32768;            // 256*1024*4 = 1,048,576 B

    hipMemsetAsync(counts, 0, NN * sizeof(int), stream);
    k_offsets<<<(NN + 255) / 256, 256, 0, stream>>>(batch_ids, offs);
    k_embed<<<NN / 8, 256, 0, stream>>>(graph_x, emb, bufA);
    k_hist<<<(E2 + 255) / 256, 256, 0, stream>>>(edge_idx, counts);
    k_bsum<<<200, 256, 0, stream>>>(counts, bsum);
    k_boff<<<1, 64, 0, stream>>>(bsum, boff);
    k_indptr<<<200, 64, 0, stream>>>(counts, boff, indptr, cursor);
    k_scatter<<<(E2 + 255) / 256, 256, 0, stream>>>(edge_idx, cursor, srcs);

    for (int l = 0; l < 3; l++) {
        k_gemm<<<(NN + 127) / 128, 256, 0, stream>>>(bufA, gat_W + l * F * F, gat_as + l * F,
                                                     gat_ad + l * F, bufB, hs_src, hs_dst);
        k_agg<<<(NN + 3) / 4, 256, 0, stream>>>(bufB, srcs, indptr, hs_src, hs_dst,
                                                gat_b + l * F, bufA, (l < 2) ? 1 : 0);
    }

    hipMemsetAsync(bufB, 0, 131072 + 1048576, stream);
    k_binsum_ctx<<<391, 256, 0, stream>>>(bufA, batch_ids, offs, seq_len, s128);
    k_binsum_hid<<<128, 256, 0, stream>>>(hidden, offs, seq_len, s1024);
    k_pool<<<NB * TP, 256, 0, stream>>>(s128, s1024, offs, seq_len,
                                        W_dc, b_dc, W_down, b_down, W_up, b_up, out);
}

// Round 4
// 608.643 us; speedup vs baseline: 2.7491x; 1.0654x over previous
//
#include <hip/hip_runtime.h>
#include <hip/hip_bf16.h>

#define NN 100000   // nodes
#define NE 800000   // edges (without self loops)
#define E2 900000   // edges + self loops
#define F  128      // KGE
#define NB 8        // batch
#define SEQ 1024
#define HID 1024
#define DWN 256
#define TP 32

// ---------------- batch offsets from sorted batch_ids ----------------
__global__ void k_offsets(const int* __restrict__ bids, int* __restrict__ offs) {
    int n = blockIdx.x * 256 + threadIdx.x;
    if (n >= NN) return;
    int b = bids[n];
    if (n == 0) offs[0] = 0;
    else if (bids[n - 1] != b) offs[b] = n;
    if (n == NN - 1) offs[b + 1] = NN;
}

// ---------------- embedding gather: x[n] = emb[graph_x[n]] ----------------
__global__ void k_embed(const int* __restrict__ gx, const float* __restrict__ emb,
                        float* __restrict__ x) {
    int i = blockIdx.x * 256 + threadIdx.x;   // over NN*32 float4 chunks
    int n = i >> 5, c = i & 31;
    float4 v = ((const float4*)(emb + (size_t)gx[n] * F))[c];
    ((float4*)(x + (size_t)n * F))[c] = v;
}

// ---------------- CSR build ----------------
__global__ void k_hist(const int* __restrict__ ei, int* __restrict__ counts) {
    int e = blockIdx.x * 256 + threadIdx.x;
    if (e >= E2) return;
    int dst = (e < NE) ? ei[NE + e] : (e - NE);
    atomicAdd(&counts[dst], 1);
}

__global__ void k_bsum(const int* __restrict__ counts, int* __restrict__ bsum) {
    __shared__ int red[256];
    int b = blockIdx.x, t = threadIdx.x;
    int base = b * 500;
    int s = 0;
    for (int i = t; i < 500; i += 256) s += counts[base + i];
    red[t] = s; __syncthreads();
    for (int o = 128; o > 0; o >>= 1) { if (t < o) red[t] += red[t + o]; __syncthreads(); }
    if (t == 0) bsum[b] = red[0];
}

__global__ void k_boff(const int* __restrict__ bsum, int* __restrict__ boff) {
    if (threadIdx.x == 0) {
        int r = 0;
        for (int i = 0; i < 200; i++) { boff[i] = r; r += bsum[i]; }
        boff[200] = r;
    }
}

// parallel block scan: indptr/cursor for 500 nodes per block
__global__ __launch_bounds__(256) void k_scan(const int* __restrict__ counts,
                                              const int* __restrict__ boff,
                                              int* __restrict__ indptr,
                                              int* __restrict__ cursor) {
    __shared__ int sa[256], sb[256];
    int b = blockIdx.x, t = threadIdx.x;
    int base = b * 500;
    int i0 = t * 2, i1 = t * 2 + 1;
    int c0 = (i0 < 500) ? counts[base + i0] : 0;
    int c1 = (i1 < 500) ? counts[base + i1] : 0;
    sa[t] = c0 + c1;
    __syncthreads();
    int* src = sa; int* dst = sb;
    for (int off = 1; off < 256; off <<= 1) {
        int v = src[t];
        if (t >= off) v += src[t - off];
        dst[t] = v;
        __syncthreads();
        int* tmp = src; src = dst; dst = tmp;
    }
    int excl = src[t] - (c0 + c1) + boff[b];
    if (i0 < 500) { indptr[base + i0] = excl; cursor[base + i0] = excl; }
    if (i1 < 500) { indptr[base + i1] = excl + c0; cursor[base + i1] = excl + c0; }
    if (b == 199 && t == 0) indptr[NN] = E2;
}

__global__ void k_scatter(const int* __restrict__ ei, int* __restrict__ cursor,
                          int* __restrict__ srcs) {
    int e = blockIdx.x * 256 + threadIdx.x;
    if (e >= E2) return;
    int src, dst;
    if (e < NE) { src = ei[e]; dst = ei[NE + e]; }
    else        { src = dst = e - NE; }
    int pos = atomicAdd(&cursor[dst], 1);
    srcs[pos] = src;
}

// ---------------- tiled GEMM: h = x @ W (bf16 out), fused hs epilogue ----------
__global__ __launch_bounds__(256) void k_gemm(
    const float* __restrict__ x, const float* __restrict__ W,
    const float* __restrict__ a_s, const float* __restrict__ a_d,
    ushort* __restrict__ hb, float* __restrict__ hs_src, float* __restrict__ hs_dst) {
    __shared__ float At[32][132];
    __shared__ float Ws[32][132];
    const int tid = threadIdx.x;
    const int ty = tid >> 4, tx = tid & 15;
    const int row0 = blockIdx.x * 128;

    float acc[8][8];
    #pragma unroll
    for (int i = 0; i < 8; i++)
        #pragma unroll
        for (int j = 0; j < 8; j++) acc[i][j] = 0.f;

    const int lr = tid >> 3;
    const int lc = tid & 7;
    const int wr = tid >> 5;
    const int wc = tid & 31;

    for (int kt = 0; kt < 4; kt++) {
        #pragma unroll
        for (int p = 0; p < 4; p++) {
            int r = lr + 32 * p;
            int rg = row0 + r; if (rg > NN - 1) rg = NN - 1;
            float4 v = *(const float4*)&x[(size_t)rg * F + kt * 32 + lc * 4];
            At[lc * 4 + 0][r] = v.x;
            At[lc * 4 + 1][r] = v.y;
            At[lc * 4 + 2][r] = v.z;
            At[lc * 4 + 3][r] = v.w;
        }
        #pragma unroll
        for (int p = 0; p < 4; p++) {
            int k = wr + 8 * p;
            float4 v = *(const float4*)&W[(size_t)(kt * 32 + k) * F + wc * 4];
            *(float4*)&Ws[k][wc * 4] = v;
        }
        __syncthreads();
        #pragma unroll 8
        for (int k = 0; k < 32; k++) {
            float4 a0 = *(const float4*)&At[k][ty * 8];
            float4 a1 = *(const float4*)&At[k][ty * 8 + 4];
            float4 w0 = *(const float4*)&Ws[k][tx * 4];
            float4 w1 = *(const float4*)&Ws[k][64 + tx * 4];
            float av[8] = {a0.x, a0.y, a0.z, a0.w, a1.x, a1.y, a1.z, a1.w};
            float wv[8] = {w0.x, w0.y, w0.z, w0.w, w1.x, w1.y, w1.z, w1.w};
            #pragma unroll
            for (int i = 0; i < 8; i++)
                #pragma unroll
                for (int j = 0; j < 8; j++)
                    acc[i][j] += av[i] * wv[j];
        }
        __syncthreads();
    }

    float4 as0 = *(const float4*)&a_s[tx * 4];
    float4 as1 = *(const float4*)&a_s[64 + tx * 4];
    float4 ad0 = *(const float4*)&a_d[tx * 4];
    float4 ad1 = *(const float4*)&a_d[64 + tx * 4];
    float asv[8] = {as0.x, as0.y, as0.z, as0.w, as1.x, as1.y, as1.z, as1.w};
    float adv[8] = {ad0.x, ad0.y, ad0.z, ad0.w, ad1.x, ad1.y, ad1.z, ad1.w};

    #pragma unroll
    for (int i = 0; i < 8; i++) {
        int rg = row0 + ty * 8 + i;
        bool ok = rg < NN;
        if (ok) {
            union { ushort u[4]; uint2 v; } p0, p1;
            #pragma unroll
            for (int j = 0; j < 4; j++) {
                __hip_bfloat16 b0 = __float2bfloat16(acc[i][j]);
                __hip_bfloat16 b1 = __float2bfloat16(acc[i][4 + j]);
                p0.u[j] = *(ushort*)&b0;
                p1.u[j] = *(ushort*)&b1;
            }
            *(uint2*)&hb[(size_t)rg * F + tx * 4] = p0.v;
            *(uint2*)&hb[(size_t)rg * F + 64 + tx * 4] = p1.v;
        }
        float ps = 0.f, pd = 0.f;
        #pragma unroll
        for (int j = 0; j < 8; j++) { ps += acc[i][j] * asv[j]; pd += acc[i][j] * adv[j]; }
        #pragma unroll
        for (int m = 8; m >= 1; m >>= 1) { ps += __shfl_xor(ps, m); pd += __shfl_xor(pd, m); }
        if (ok && tx == 0) { hs_src[rg] = ps; hs_dst[rg] = pd; }
    }
}

// ---------------- per-node GAT aggregation (softmax over in-edges) ----------------
// bf16 h gather (256B/row); deg<=64 fast path computes e once in registers.
__global__ __launch_bounds__(256) void k_agg(
    const ushort* __restrict__ hb, const int* __restrict__ srcs,
    const int* __restrict__ indptr, const float* __restrict__ hs_src,
    const float* __restrict__ hs_dst, const float* __restrict__ bias,
    float* __restrict__ out, int do_relu) {
    int wave = threadIdx.x >> 6, lane = threadIdx.x & 63;
    int i = blockIdx.x * 4 + wave;
    if (i >= NN) return;
    int p0 = indptr[i], p1 = indptr[i + 1];
    int deg = p1 - p0;
    float hd = hs_dst[i];
    float accx = 0.f, accy = 0.f, dl = 0.f;

    if (deg <= 64) {
        int s = 0; float e = -1e30f;
        if (lane < deg) {
            s = srcs[p0 + lane];
            float t0 = hs_src[s] + hd;
            e = t0 > 0.f ? t0 : 0.2f * t0;
        }
        float m = e;
        #pragma unroll
        for (int o = 32; o > 0; o >>= 1) m = fmaxf(m, __shfl_xor(m, o));
        float ex = (lane < deg) ? __expf(e - m) : 0.f;
        dl = ex;
        for (int j = 0; j < deg; j++) {
            float exj = __shfl(ex, j);
            int sj = __shfl(s, j);
            uint hv = ((const uint*)(hb + (size_t)sj * F))[lane];
            accx += exj * __uint_as_float(hv << 16);
            accy += exj * __uint_as_float(hv & 0xffff0000u);
        }
    } else {
        float m = -1e30f;
        for (int p = p0 + lane; p < p1; p += 64) {
            int s = srcs[p];
            float e = hs_src[s] + hd;
            e = e > 0.f ? e : 0.2f * e;
            m = fmaxf(m, e);
        }
        #pragma unroll
        for (int o = 32; o > 0; o >>= 1) m = fmaxf(m, __shfl_xor(m, o));
        for (int base = p0; base < p1; base += 64) {
            int cn = min(64, p1 - base);
            int s = 0; float ex = 0.f;
            if (lane < cn) {
                s = srcs[base + lane];
                float e = hs_src[s] + hd;
                e = e > 0.f ? e : 0.2f * e;
                ex = __expf(e - m);
            }
            dl += ex;
            for (int j = 0; j < cn; j++) {
                float exj = __shfl(ex, j);
                int sj = __shfl(s, j);
                uint hv = ((const uint*)(hb + (size_t)sj * F))[lane];
                accx += exj * __uint_as_float(hv << 16);
                accy += exj * __uint_as_float(hv & 0xffff0000u);
            }
        }
    }
    #pragma unroll
    for (int o = 32; o > 0; o >>= 1) dl += __shfl_xor(dl, o);
    float inv = 1.f / dl;
    float2 b2 = ((const float2*)bias)[lane];
    float ox = accx * inv + b2.x;
    float oy = accy * inv + b2.y;
    if (do_relu) { ox = fmaxf(ox, 0.f); oy = fmaxf(oy, 0.f); }
    float2 o; o.x = ox; o.y = oy;
    ((float2*)(out + (size_t)i * F))[lane] = o;
}

// ---------------- bin sums: ctx rows (x3, 128 cols) ----------------
__global__ __launch_bounds__(256) void k_binsum_ctx(
    const float* __restrict__ x3, const int* __restrict__ bids,
    const int* __restrict__ offs, const int* __restrict__ seq_len,
    float* __restrict__ s128) {
    int wid = blockIdx.x * 4 + (threadIdx.x >> 6);
    int lane = threadIdx.x & 63;
    int r0 = wid * 64;
    if (r0 >= NN) return;
    int r1 = min(r0 + 64, NN);
    float ax = 0.f, ay = 0.f;
    int cur = -1;
    int cb = -1, off = 0, C = 0, L = 1;
    for (int r = r0; r < r1; r++) {
        int b = bids[r];
        if (b != cb) { cb = b; off = offs[b]; C = offs[b + 1] - off; L = C + seq_len[b]; }
        int q = r - off;
        int tmin = (q * TP) / L;
        int tmax = ((q + 1) * TP - 1) / L;
        float2 v = ((const float2*)(x3 + (size_t)r * F))[lane];
        int bin = b * TP + tmin;
        if (bin != cur) {
            if (cur >= 0) {
                atomicAdd(&s128[(size_t)cur * F + 2 * lane], ax);
                atomicAdd(&s128[(size_t)cur * F + 2 * lane + 1], ay);
            }
            cur = bin; ax = 0.f; ay = 0.f;
        }
        ax += v.x; ay += v.y;
        if (tmax != tmin) {
            atomicAdd(&s128[(size_t)(b * TP + tmax) * F + 2 * lane], v.x);
            atomicAdd(&s128[(size_t)(b * TP + tmax) * F + 2 * lane + 1], v.y);
        }
    }
    if (cur >= 0) {
        atomicAdd(&s128[(size_t)cur * F + 2 * lane], ax);
        atomicAdd(&s128[(size_t)cur * F + 2 * lane + 1], ay);
    }
}

// ---------------- bin sums: hidden rows (1024 cols), 8-row chunks ----------------
__global__ __launch_bounds__(256) void k_binsum_hid(
    const float* __restrict__ hidden, const int* __restrict__ offs,
    const int* __restrict__ seq_len, float* __restrict__ s1024) {
    int wid = blockIdx.x * 4 + (threadIdx.x >> 6);   // 0..1023
    int lane = threadIdx.x & 63;
    int b = wid >> 7;          // 128 chunks per batch
    int chunk = wid & 127;
    int sl = seq_len[b];
    int r0 = chunk * 8;
    if (r0 >= sl) return;
    int r1 = min(r0 + 8, sl);
    int C = offs[b + 1] - offs[b];
    int L = C + sl;
    float a[16];
    #pragma unroll
    for (int c = 0; c < 16; c++) a[c] = 0.f;
    int cur = -1;
    const float* hbase = hidden + (size_t)b * SEQ * HID;
    for (int r = r0; r < r1; r++) {
        int q = C + r;
        int tmin = (q * TP) / L;
        int tmax = ((q + 1) * TP - 1) / L;
        const float4* row = (const float4*)(hbase + (size_t)r * HID);
        float4 v0 = row[lane], v1 = row[64 + lane], v2 = row[128 + lane], v3 = row[192 + lane];
        int bin = b * TP + tmin;
        if (bin != cur) {
            if (cur >= 0) {
                float* dst = s1024 + (size_t)cur * HID;
                #pragma unroll
                for (int c = 0; c < 4; c++) atomicAdd(&dst[4 * lane + c], a[c]);
                #pragma unroll
                for (int c = 0; c < 4; c++) atomicAdd(&dst[256 + 4 * lane + c], a[4 + c]);
                #pragma unroll
                for (int c = 0; c < 4; c++) atomicAdd(&dst[512 + 4 * lane + c], a[8 + c]);
                #pragma unroll
                for (int c = 0; c < 4; c++) atomicAdd(&dst[768 + 4 * lane + c], a[12 + c]);
            }
            cur = bin;
            #pragma unroll
            for (int c = 0; c < 16; c++) a[c] = 0.f;
        }
        a[0] += v0.x; a[1] += v0.y; a[2] += v0.z; a[3] += v0.w;
        a[4] += v1.x; a[5] += v1.y; a[6] += v1.z; a[7] += v1.w;
        a[8] += v2.x; a[9] += v2.y; a[10] += v2.z; a[11] += v2.w;
        a[12] += v3.x; a[13] += v3.y; a[14] += v3.z; a[15] += v3.w;
        if (tmax != tmin) {
            float* dst = s1024 + (size_t)(b * TP + tmax) * HID;
            atomicAdd(&dst[4 * lane + 0], v0.x); atomicAdd(&dst[4 * lane + 1], v0.y);
            atomicAdd(&dst[4 * lane + 2], v0.z); atomicAdd(&dst[4 * lane + 3], v0.w);
            atomicAdd(&dst[256 + 4 * lane + 0], v1.x); atomicAdd(&dst[256 + 4 * lane + 1], v1.y);
            atomicAdd(&dst[256 + 4 * lane + 2], v1.z); atomicAdd(&dst[256 + 4 * lane + 3], v1.w);
            atomicAdd(&dst[512 + 4 * lane + 0], v2.x); atomicAdd(&dst[512 + 4 * lane + 1], v2.y);
            atomicAdd(&dst[512 + 4 * lane + 2], v2.z); atomicAdd(&dst[512 + 4 * lane + 3], v2.w);
            atomicAdd(&dst[768 + 4 * lane + 0], v3.x); atomicAdd(&dst[768 + 4 * lane + 1], v3.y);
            atomicAdd(&dst[768 + 4 * lane + 2], v3.z); atomicAdd(&dst[768 + 4 * lane + 3], v3.w);
        }
    }
    if (cur >= 0) {
        float* dst = s1024 + (size_t)cur * HID;
        #pragma unroll
        for (int c = 0; c < 4; c++) atomicAdd(&dst[4 * lane + c], a[c]);
        #pragma unroll
        for (int c = 0; c < 4; c++) atomicAdd(&dst[256 + 4 * lane + c], a[4 + c]);
        #pragma unroll
        for (int c = 0; c < 4; c++) atomicAdd(&dst[512 + 4 * lane + c], a[8 + c]);
        #pragma unroll
        for (int c = 0; c < 4; c++) atomicAdd(&dst[768 + 4 * lane + c], a[12 + c]);
    }
}

// ---------------- final: pooled -> silu -> up-proj ----------------
__global__ __launch_bounds__(256) void k_pool(
    const float* __restrict__ s128, const float* __restrict__ s1024,
    const int* __restrict__ offs, const int* __restrict__ seq_len,
    const float* __restrict__ W_dc, const float* __restrict__ b_dc,
    const float* __restrict__ W_down, const float* __restrict__ b_down,
    const float* __restrict__ W_up, const float* __restrict__ b_up,
    float* __restrict__ out) {
    int b = blockIdx.x >> 5;
    int t = blockIdx.x & 31;
    int tid = threadIdx.x;
    int bin = blockIdx.x;
    __shared__ float sh128[F];
    __shared__ float sh1024[HID];
    __shared__ float sp[DWN];
    int C = offs[b + 1] - offs[b];
    int sl = seq_len[b];
    int L = C + sl;
    int start = (t * L) / TP;
    int end = ((t + 1) * L + TP - 1) / TP;
    int cnt = end - start;
    int ce = min(end, C);
    int n_ctx = max(ce - start, 0);
    int n_hs = max(end - C, 0) - max(start - C, 0);
    if (tid < F) sh128[tid] = s128[(size_t)bin * F + tid];
    #pragma unroll
    for (int c = 0; c < 4; c++) sh1024[tid + 256 * c] = s1024[(size_t)bin * HID + tid + 256 * c];
    __syncthreads();
    {
        float p = (float)n_ctx * b_dc[tid] + (float)n_hs * b_down[tid];
        for (int k = 0; k < F; k++)   p += sh128[k] * W_dc[k * DWN + tid];
        for (int k = 0; k < HID; k++) p += sh1024[k] * W_down[k * DWN + tid];
        p /= (float)cnt;
        sp[tid] = p / (1.f + __expf(-p));
    }
    __syncthreads();
    {
        int o = tid * 4;
        float4 acc = *(const float4*)&b_up[o];
        for (int k = 0; k < DWN; k++) {
            float s = sp[k];
            float4 w = *(const float4*)&W_up[(size_t)k * HID + o];
            acc.x += s * w.x; acc.y += s * w.y; acc.z += s * w.z; acc.w += s * w.w;
        }
        *(float4*)&out[((size_t)(b * TP + t)) * HID + o] = acc;
    }
}

extern "C" void kernel_launch(void* const* d_in, const int* in_sizes, int n_in,
                              void* d_out, int out_size, void* d_ws, size_t ws_size,
                              hipStream_t stream) {
    const int*   graph_x   = (const int*)d_in[0];
    const int*   edge_idx  = (const int*)d_in[1];
    const int*   batch_ids = (const int*)d_in[2];
    const float* hidden    = (const float*)d_in[3];
    const int*   seq_len   = (const int*)d_in[4];
    const float* emb       = (const float*)d_in[5];
    const float* gat_W     = (const float*)d_in[6];
    const float* gat_as    = (const float*)d_in[7];
    const float* gat_ad    = (const float*)d_in[8];
    const float* gat_b     = (const float*)d_in[9];
    const float* W_down    = (const float*)d_in[10];
    const float* b_down    = (const float*)d_in[11];
    const float* W_dc      = (const float*)d_in[12];
    const float* b_dc      = (const float*)d_in[13];
    const float* W_up      = (const float*)d_in[14];
    const float* b_up      = (const float*)d_in[15];
    float* out = (float*)d_out;

    char* ws = (char*)d_ws;
    float*  bufA   = (float*) (ws);                   // 51,200,000 B  (x)
    ushort* hb     = (ushort*)(ws + 51200000);        // 25,600,000 B  (h bf16)
    float*  hs_src = (float*) (ws + 102400000);
    float*  hs_dst = (float*) (ws + 102800000);
    int*    counts = (int*)   (ws + 103200000);
    int*    indptr = (int*)   (ws + 103600000);
    int*    cursor = (int*)   (ws + 104000128);
    int*    srcs   = (int*)   (ws + 104400128);
    int*    bsum   = (int*)   (ws + 108000128);
    int*    boff   = (int*)   (ws + 108001128);
    int*    offs   = (int*)   (ws + 108002128);
    // bin tables overlay the hb region (h dead after last k_agg)
    float* s128   = (float*)(ws + 51200000);          // 131,072 B
    float* s1024  = (float*)(ws + 51200000 + 131072); // 1,048,576 B

    hipMemsetAsync(counts, 0, NN * sizeof(int), stream);
    k_offsets<<<(NN + 255) / 256, 256, 0, stream>>>(batch_ids, offs);
    k_embed<<<NN / 8, 256, 0, stream>>>(graph_x, emb, bufA);
    k_hist<<<(E2 + 255) / 256, 256, 0, stream>>>(edge_idx, counts);
    k_bsum<<<200, 256, 0, stream>>>(counts, bsum);
    k_boff<<<1, 64, 0, stream>>>(bsum, boff);
    k_scan<<<200, 256, 0, stream>>>(counts, boff, indptr, cursor);
    k_scatter<<<(E2 + 255) / 256, 256, 0, stream>>>(edge_idx, cursor, srcs);

    for (int l = 0; l < 3; l++) {
        k_gemm<<<(NN + 127) / 128, 256, 0, stream>>>(bufA, gat_W + l * F * F, gat_as + l * F,
                                                     gat_ad + l * F, hb, hs_src, hs_dst);
        k_agg<<<(NN + 3) / 4, 256, 0, stream>>>(hb, srcs, indptr, hs_src, hs_dst,
                                                gat_b + l * F, bufA, (l < 2) ? 1 : 0);
    }

    hipMemsetAsync((void*)s128, 0, 131072 + 1048576, stream);
    k_binsum_ctx<<<391, 256, 0, stream>>>(bufA, batch_ids, offs, seq_len, s128);
    k_binsum_hid<<<256, 256, 0, stream>>>(hidden, offs, seq_len, s1024);
    k_pool<<<NB * TP, 256, 0, stream>>>(s128, s1024, offs, seq_len,
                                        W_dc, b_dc, W_down, b_down, W_up, b_up, out);
}

// Round 5
// 536.328 us; speedup vs baseline: 3.1198x; 1.1348x over previous
//
#include <hip/hip_runtime.h>
#include <hip/hip_bf16.h>

#define NN 100000   // nodes
#define NE 800000   // edges (without self loops)
#define E2 900000   // edges + self loops
#define F  128      // KGE
#define NB 8        // batch
#define SEQ 1024
#define HID 1024
#define DWN 256
#define TP 32

__device__ __forceinline__ float BL(uint u) { return __uint_as_float(u << 16); }
__device__ __forceinline__ float BH(uint u) { return __uint_as_float(u & 0xffff0000u); }
__device__ __forceinline__ uint PK(float lo, float hi) {
    __hip_bfloat16 a = __float2bfloat16(lo);
    __hip_bfloat16 b = __float2bfloat16(hi);
    return (uint)(*(ushort*)&a) | ((uint)(*(ushort*)&b) << 16);
}

// ---------------- batch offsets from sorted batch_ids ----------------
__global__ void k_offsets(const int* __restrict__ bids, int* __restrict__ offs) {
    int n = blockIdx.x * 256 + threadIdx.x;
    if (n >= NN) return;
    int b = bids[n];
    if (n == 0) offs[0] = 0;
    else if (bids[n - 1] != b) offs[b] = n;
    if (n == NN - 1) offs[b + 1] = NN;
}

// ---------------- embedding gather: x[n] = bf16(emb[graph_x[n]]) ----------------
__global__ void k_embed(const int* __restrict__ gx, const float* __restrict__ emb,
                        ushort* __restrict__ x) {
    int i = blockIdx.x * 256 + threadIdx.x;   // over NN*16 chunks of 8 cols
    int n = i >> 4, c = i & 15;
    const float4* src = (const float4*)(emb + (size_t)gx[n] * F + c * 8);
    float4 a = src[0], b = src[1];
    uint4 o;
    o.x = PK(a.x, a.y); o.y = PK(a.z, a.w);
    o.z = PK(b.x, b.y); o.w = PK(b.z, b.w);
    *(uint4*)&x[(size_t)n * F + c * 8] = o;
}

// ---------------- CSR build ----------------
__global__ void k_hist(const int* __restrict__ ei, int* __restrict__ counts) {
    int e = blockIdx.x * 256 + threadIdx.x;
    if (e >= E2) return;
    int dst = (e < NE) ? ei[NE + e] : (e - NE);
    atomicAdd(&counts[dst], 1);
}

__global__ void k_bsum(const int* __restrict__ counts, int* __restrict__ bsum) {
    __shared__ int red[256];
    int b = blockIdx.x, t = threadIdx.x;
    int base = b * 500;
    int s = 0;
    for (int i = t; i < 500; i += 256) s += counts[base + i];
    red[t] = s; __syncthreads();
    for (int o = 128; o > 0; o >>= 1) { if (t < o) red[t] += red[t + o]; __syncthreads(); }
    if (t == 0) bsum[b] = red[0];
}

__global__ void k_boff(const int* __restrict__ bsum, int* __restrict__ boff) {
    if (threadIdx.x == 0) {
        int r = 0;
        for (int i = 0; i < 200; i++) { boff[i] = r; r += bsum[i]; }
        boff[200] = r;
    }
}

__global__ __launch_bounds__(256) void k_scan(const int* __restrict__ counts,
                                              const int* __restrict__ boff,
                                              int* __restrict__ indptr,
                                              int* __restrict__ cursor) {
    __shared__ int sa[256], sb[256];
    int b = blockIdx.x, t = threadIdx.x;
    int base = b * 500;
    int i0 = t * 2, i1 = t * 2 + 1;
    int c0 = (i0 < 500) ? counts[base + i0] : 0;
    int c1 = (i1 < 500) ? counts[base + i1] : 0;
    sa[t] = c0 + c1;
    __syncthreads();
    int* src = sa; int* dst = sb;
    for (int off = 1; off < 256; off <<= 1) {
        int v = src[t];
        if (t >= off) v += src[t - off];
        dst[t] = v;
        __syncthreads();
        int* tmp = src; src = dst; dst = tmp;
    }
    int excl = src[t] - (c0 + c1) + boff[b];
    if (i0 < 500) { indptr[base + i0] = excl; cursor[base + i0] = excl; }
    if (i1 < 500) { indptr[base + i1] = excl + c0; cursor[base + i1] = excl + c0; }
    if (b == 199 && t == 0) indptr[NN] = E2;
}

__global__ void k_scatter(const int* __restrict__ ei, int* __restrict__ cursor,
                          int* __restrict__ srcs) {
    int e = blockIdx.x * 256 + threadIdx.x;
    if (e >= E2) return;
    int src, dst;
    if (e < NE) { src = ei[e]; dst = ei[NE + e]; }
    else        { src = dst = e - NE; }
    int pos = atomicAdd(&cursor[dst], 1);
    srcs[pos] = src;
}

// ---------------- tiled GEMM: h = x @ W (bf16 in/out), fused hs epilogue ----------
__global__ __launch_bounds__(256) void k_gemm(
    const ushort* __restrict__ xb, const float* __restrict__ W,
    const float* __restrict__ a_s, const float* __restrict__ a_d,
    ushort* __restrict__ hb, float* __restrict__ hs_src, float* __restrict__ hs_dst) {
    __shared__ float At[32][132];
    __shared__ float Ws[32][132];
    const int tid = threadIdx.x;
    const int ty = tid >> 4, tx = tid & 15;
    const int row0 = blockIdx.x * 128;

    float acc[8][8];
    #pragma unroll
    for (int i = 0; i < 8; i++)
        #pragma unroll
        for (int j = 0; j < 8; j++) acc[i][j] = 0.f;

    const int wr = tid >> 5;
    const int wc = tid & 31;

    for (int kt = 0; kt < 4; kt++) {
        // A-tile: bf16 -> f32 transposed stage. li = p*256+tid; row=li&127 (lanes
        // span 64 consecutive rows -> conflict-free column writes), cg=li>>7.
        #pragma unroll
        for (int p = 0; p < 2; p++) {
            int li = p * 256 + tid;
            int row = li & 127, cg = li >> 7;
            int rg = row0 + row; if (rg > NN - 1) rg = NN - 1;
            uint4 v = *(const uint4*)&xb[(size_t)rg * F + kt * 32 + cg * 8];
            At[cg * 8 + 0][row] = BL(v.x); At[cg * 8 + 1][row] = BH(v.x);
            At[cg * 8 + 2][row] = BL(v.y); At[cg * 8 + 3][row] = BH(v.y);
            At[cg * 8 + 4][row] = BL(v.z); At[cg * 8 + 5][row] = BH(v.z);
            At[cg * 8 + 6][row] = BL(v.w); At[cg * 8 + 7][row] = BH(v.w);
        }
        #pragma unroll
        for (int p = 0; p < 4; p++) {
            int k = wr + 8 * p;
            float4 v = *(const float4*)&W[(size_t)(kt * 32 + k) * F + wc * 4];
            *(float4*)&Ws[k][wc * 4] = v;
        }
        __syncthreads();
        #pragma unroll 8
        for (int k = 0; k < 32; k++) {
            float4 a0 = *(const float4*)&At[k][ty * 8];
            float4 a1 = *(const float4*)&At[k][ty * 8 + 4];
            float4 w0 = *(const float4*)&Ws[k][tx * 4];
            float4 w1 = *(const float4*)&Ws[k][64 + tx * 4];
            float av[8] = {a0.x, a0.y, a0.z, a0.w, a1.x, a1.y, a1.z, a1.w};
            float wv[8] = {w0.x, w0.y, w0.z, w0.w, w1.x, w1.y, w1.z, w1.w};
            #pragma unroll
            for (int i = 0; i < 8; i++)
                #pragma unroll
                for (int j = 0; j < 8; j++)
                    acc[i][j] += av[i] * wv[j];
        }
        __syncthreads();
    }

    float4 as0 = *(const float4*)&a_s[tx * 4];
    float4 as1 = *(const float4*)&a_s[64 + tx * 4];
    float4 ad0 = *(const float4*)&a_d[tx * 4];
    float4 ad1 = *(const float4*)&a_d[64 + tx * 4];
    float asv[8] = {as0.x, as0.y, as0.z, as0.w, as1.x, as1.y, as1.z, as1.w};
    float adv[8] = {ad0.x, ad0.y, ad0.z, ad0.w, ad1.x, ad1.y, ad1.z, ad1.w};

    #pragma unroll
    for (int i = 0; i < 8; i++) {
        int rg = row0 + ty * 8 + i;
        bool ok = rg < NN;
        if (ok) {
            uint2 p0, p1;
            p0.x = PK(acc[i][0], acc[i][1]); p0.y = PK(acc[i][2], acc[i][3]);
            p1.x = PK(acc[i][4], acc[i][5]); p1.y = PK(acc[i][6], acc[i][7]);
            *(uint2*)&hb[(size_t)rg * F + tx * 4] = p0;
            *(uint2*)&hb[(size_t)rg * F + 64 + tx * 4] = p1;
        }
        float ps = 0.f, pd = 0.f;
        #pragma unroll
        for (int j = 0; j < 8; j++) { ps += acc[i][j] * asv[j]; pd += acc[i][j] * adv[j]; }
        #pragma unroll
        for (int m = 8; m >= 1; m >>= 1) { ps += __shfl_xor(ps, m); pd += __shfl_xor(pd, m); }
        if (ok && tx == 0) { hs_src[rg] = ps; hs_dst[rg] = pd; }
    }
}

// ---------------- per-node GAT aggregation (softmax over in-edges) ----------------
// (src,exp) staged in LDS; gather unrolled x4 with 4 independent acc pairs.
__global__ __launch_bounds__(256) void k_agg(
    const ushort* __restrict__ hb, const int* __restrict__ srcs,
    const int* __restrict__ indptr, const float* __restrict__ hs_src,
    const float* __restrict__ hs_dst, const float* __restrict__ bias,
    ushort* __restrict__ xout, int do_relu) {
    __shared__ uint2 se[4][64];
    int wave = threadIdx.x >> 6, lane = threadIdx.x & 63;
    int i = blockIdx.x * 4 + wave;
    if (i >= NN) return;
    int p0 = indptr[i], p1 = indptr[i + 1];
    int deg = p1 - p0;
    float hd = hs_dst[i];
    float ax0 = 0.f, ay0 = 0.f, ax1 = 0.f, ay1 = 0.f;
    float ax2 = 0.f, ay2 = 0.f, ax3 = 0.f, ay3 = 0.f, dl = 0.f;

    if (deg <= 64) {
        int s = 0; float e = -1e30f;
        if (lane < deg) {
            s = srcs[p0 + lane];
            float t0 = hs_src[s] + hd;
            e = t0 > 0.f ? t0 : 0.2f * t0;
        }
        float m = e;
        #pragma unroll
        for (int o = 32; o > 0; o >>= 1) m = fmaxf(m, __shfl_xor(m, o));
        float ex = (lane < deg) ? __expf(e - m) : 0.f;
        dl = ex;
        se[wave][lane] = make_uint2((unsigned)s, __float_as_uint(ex));
        int j = 0;
        for (; j + 4 <= deg; j += 4) {
            uint2 q0 = se[wave][j + 0], q1 = se[wave][j + 1];
            uint2 q2 = se[wave][j + 2], q3 = se[wave][j + 3];
            uint h0 = ((const uint*)(hb + (size_t)q0.x * F))[lane];
            uint h1 = ((const uint*)(hb + (size_t)q1.x * F))[lane];
            uint h2 = ((const uint*)(hb + (size_t)q2.x * F))[lane];
            uint h3 = ((const uint*)(hb + (size_t)q3.x * F))[lane];
            float e0 = __uint_as_float(q0.y), e1 = __uint_as_float(q1.y);
            float e2 = __uint_as_float(q2.y), e3 = __uint_as_float(q3.y);
            ax0 += e0 * BL(h0); ay0 += e0 * BH(h0);
            ax1 += e1 * BL(h1); ay1 += e1 * BH(h1);
            ax2 += e2 * BL(h2); ay2 += e2 * BH(h2);
            ax3 += e3 * BL(h3); ay3 += e3 * BH(h3);
        }
        for (; j < deg; j++) {
            uint2 q = se[wave][j];
            uint h = ((const uint*)(hb + (size_t)q.x * F))[lane];
            float e0 = __uint_as_float(q.y);
            ax0 += e0 * BL(h); ay0 += e0 * BH(h);
        }
    } else {
        float m = -1e30f;
        for (int p = p0 + lane; p < p1; p += 64) {
            int s = srcs[p];
            float e = hs_src[s] + hd;
            e = e > 0.f ? e : 0.2f * e;
            m = fmaxf(m, e);
        }
        #pragma unroll
        for (int o = 32; o > 0; o >>= 1) m = fmaxf(m, __shfl_xor(m, o));
        for (int base = p0; base < p1; base += 64) {
            int cn = min(64, p1 - base);
            int s = 0; float ex = 0.f;
            if (lane < cn) {
                s = srcs[base + lane];
                float e = hs_src[s] + hd;
                e = e > 0.f ? e : 0.2f * e;
                ex = __expf(e - m);
            }
            dl += ex;
            se[wave][lane] = make_uint2((unsigned)s, __float_as_uint(ex));
            int j = 0;
            for (; j + 4 <= cn; j += 4) {
                uint2 q0 = se[wave][j + 0], q1 = se[wave][j + 1];
                uint2 q2 = se[wave][j + 2], q3 = se[wave][j + 3];
                uint h0 = ((const uint*)(hb + (size_t)q0.x * F))[lane];
                uint h1 = ((const uint*)(hb + (size_t)q1.x * F))[lane];
                uint h2 = ((const uint*)(hb + (size_t)q2.x * F))[lane];
                uint h3 = ((const uint*)(hb + (size_t)q3.x * F))[lane];
                float e0 = __uint_as_float(q0.y), e1 = __uint_as_float(q1.y);
                float e2 = __uint_as_float(q2.y), e3 = __uint_as_float(q3.y);
                ax0 += e0 * BL(h0); ay0 += e0 * BH(h0);
                ax1 += e1 * BL(h1); ay1 += e1 * BH(h1);
                ax2 += e2 * BL(h2); ay2 += e2 * BH(h2);
                ax3 += e3 * BL(h3); ay3 += e3 * BH(h3);
            }
            for (; j < cn; j++) {
                uint2 q = se[wave][j];
                uint h = ((const uint*)(hb + (size_t)q.x * F))[lane];
                float e0 = __uint_as_float(q.y);
                ax0 += e0 * BL(h); ay0 += e0 * BH(h);
            }
        }
    }
    float accx = (ax0 + ax1) + (ax2 + ax3);
    float accy = (ay0 + ay1) + (ay2 + ay3);
    #pragma unroll
    for (int o = 32; o > 0; o >>= 1) dl += __shfl_xor(dl, o);
    float inv = 1.f / dl;
    float2 b2 = ((const float2*)bias)[lane];
    float ox = accx * inv + b2.x;
    float oy = accy * inv + b2.y;
    if (do_relu) { ox = fmaxf(ox, 0.f); oy = fmaxf(oy, 0.f); }
    ((uint*)xout)[(size_t)i * 64 + lane] = PK(ox, oy);
}

// ---------------- bin sums: ctx rows (x3 bf16, 128 cols) ----------------
__global__ __launch_bounds__(256) void k_binsum_ctx(
    const ushort* __restrict__ x3, const int* __restrict__ bids,
    const int* __restrict__ offs, const int* __restrict__ seq_len,
    float* __restrict__ s128) {
    int wid = blockIdx.x * 4 + (threadIdx.x >> 6);
    int lane = threadIdx.x & 63;
    int r0 = wid * 64;
    if (r0 >= NN) return;
    int r1 = min(r0 + 64, NN);
    float ax = 0.f, ay = 0.f;
    int cur = -1;
    int cb = -1, off = 0, C = 0, L = 1;
    for (int r = r0; r < r1; r++) {
        int b = bids[r];
        if (b != cb) { cb = b; off = offs[b]; C = offs[b + 1] - off; L = C + seq_len[b]; }
        int q = r - off;
        int tmin = (q * TP) / L;
        int tmax = ((q + 1) * TP - 1) / L;
        uint v = ((const uint*)(x3 + (size_t)r * F))[lane];
        float vx = BL(v), vy = BH(v);
        int bin = b * TP + tmin;
        if (bin != cur) {
            if (cur >= 0) {
                atomicAdd(&s128[(size_t)cur * F + 2 * lane], ax);
                atomicAdd(&s128[(size_t)cur * F + 2 * lane + 1], ay);
            }
            cur = bin; ax = 0.f; ay = 0.f;
        }
        ax += vx; ay += vy;
        if (tmax != tmin) {
            atomicAdd(&s128[(size_t)(b * TP + tmax) * F + 2 * lane], vx);
            atomicAdd(&s128[(size_t)(b * TP + tmax) * F + 2 * lane + 1], vy);
        }
    }
    if (cur >= 0) {
        atomicAdd(&s128[(size_t)cur * F + 2 * lane], ax);
        atomicAdd(&s128[(size_t)cur * F + 2 * lane + 1], ay);
    }
}

// ---------------- bin sums: hidden rows (1024 cols), 8-row chunks ----------------
__global__ __launch_bounds__(256) void k_binsum_hid(
    const float* __restrict__ hidden, const int* __restrict__ offs,
    const int* __restrict__ seq_len, float* __restrict__ s1024) {
    int wid = blockIdx.x * 4 + (threadIdx.x >> 6);   // 0..1023
    int lane = threadIdx.x & 63;
    int b = wid >> 7;          // 128 chunks per batch
    int chunk = wid & 127;
    int sl = seq_len[b];
    int r0 = chunk * 8;
    if (r0 >= sl) return;
    int r1 = min(r0 + 8, sl);
    int C = offs[b + 1] - offs[b];
    int L = C + sl;
    float a[16];
    #pragma unroll
    for (int c = 0; c < 16; c++) a[c] = 0.f;
    int cur = -1;
    const float* hbase = hidden + (size_t)b * SEQ * HID;
    for (int r = r0; r < r1; r++) {
        int q = C + r;
        int tmin = (q * TP) / L;
        int tmax = ((q + 1) * TP - 1) / L;
        const float4* row = (const float4*)(hbase + (size_t)r * HID);
        float4 v0 = row[lane], v1 = row[64 + lane], v2 = row[128 + lane], v3 = row[192 + lane];
        int bin = b * TP + tmin;
        if (bin != cur) {
            if (cur >= 0) {
                float* dst = s1024 + (size_t)cur * HID;
                #pragma unroll
                for (int c = 0; c < 4; c++) atomicAdd(&dst[4 * lane + c], a[c]);
                #pragma unroll
                for (int c = 0; c < 4; c++) atomicAdd(&dst[256 + 4 * lane + c], a[4 + c]);
                #pragma unroll
                for (int c = 0; c < 4; c++) atomicAdd(&dst[512 + 4 * lane + c], a[8 + c]);
                #pragma unroll
                for (int c = 0; c < 4; c++) atomicAdd(&dst[768 + 4 * lane + c], a[12 + c]);
            }
            cur = bin;
            #pragma unroll
            for (int c = 0; c < 16; c++) a[c] = 0.f;
        }
        a[0] += v0.x; a[1] += v0.y; a[2] += v0.z; a[3] += v0.w;
        a[4] += v1.x; a[5] += v1.y; a[6] += v1.z; a[7] += v1.w;
        a[8] += v2.x; a[9] += v2.y; a[10] += v2.z; a[11] += v2.w;
        a[12] += v3.x; a[13] += v3.y; a[14] += v3.z; a[15] += v3.w;
        if (tmax != tmin) {
            float* dst = s1024 + (size_t)(b * TP + tmax) * HID;
            atomicAdd(&dst[4 * lane + 0], v0.x); atomicAdd(&dst[4 * lane + 1], v0.y);
            atomicAdd(&dst[4 * lane + 2], v0.z); atomicAdd(&dst[4 * lane + 3], v0.w);
            atomicAdd(&dst[256 + 4 * lane + 0], v1.x); atomicAdd(&dst[256 + 4 * lane + 1], v1.y);
            atomicAdd(&dst[256 + 4 * lane + 2], v1.z); atomicAdd(&dst[256 + 4 * lane + 3], v1.w);
            atomicAdd(&dst[512 + 4 * lane + 0], v2.x); atomicAdd(&dst[512 + 4 * lane + 1], v2.y);
            atomicAdd(&dst[512 + 4 * lane + 2], v2.z); atomicAdd(&dst[512 + 4 * lane + 3], v2.w);
            atomicAdd(&dst[768 + 4 * lane + 0], v3.x); atomicAdd(&dst[768 + 4 * lane + 1], v3.y);
            atomicAdd(&dst[768 + 4 * lane + 2], v3.z); atomicAdd(&dst[768 + 4 * lane + 3], v3.w);
        }
    }
    if (cur >= 0) {
        float* dst = s1024 + (size_t)cur * HID;
        #pragma unroll
        for (int c = 0; c < 4; c++) atomicAdd(&dst[4 * lane + c], a[c]);
        #pragma unroll
        for (int c = 0; c < 4; c++) atomicAdd(&dst[256 + 4 * lane + c], a[4 + c]);
        #pragma unroll
        for (int c = 0; c < 4; c++) atomicAdd(&dst[512 + 4 * lane + c], a[8 + c]);
        #pragma unroll
        for (int c = 0; c < 4; c++) atomicAdd(&dst[768 + 4 * lane + c], a[12 + c]);
    }
}

// ---------------- final: pooled -> silu -> up-proj ----------------
__global__ __launch_bounds__(256) void k_pool(
    const float* __restrict__ s128, const float* __restrict__ s1024,
    const int* __restrict__ offs, const int* __restrict__ seq_len,
    const float* __restrict__ W_dc, const float* __restrict__ b_dc,
    const float* __restrict__ W_down, const float* __restrict__ b_down,
    const float* __restrict__ W_up, const float* __restrict__ b_up,
    float* __restrict__ out) {
    int b = blockIdx.x >> 5;
    int t = blockIdx.x & 31;
    int tid = threadIdx.x;
    int bin = blockIdx.x;
    __shared__ float sh128[F];
    __shared__ float sh1024[HID];
    __shared__ float sp[DWN];
    int C = offs[b + 1] - offs[b];
    int sl = seq_len[b];
    int L = C + sl;
    int start = (t * L) / TP;
    int end = ((t + 1) * L + TP - 1) / TP;
    int cnt = end - start;
    int ce = min(end, C);
    int n_ctx = max(ce - start, 0);
    int n_hs = max(end - C, 0) - max(start - C, 0);
    if (tid < F) sh128[tid] = s128[(size_t)bin * F + tid];
    #pragma unroll
    for (int c = 0; c < 4; c++) sh1024[tid + 256 * c] = s1024[(size_t)bin * HID + tid + 256 * c];
    __syncthreads();
    {
        float p = (float)n_ctx * b_dc[tid] + (float)n_hs * b_down[tid];
        for (int k = 0; k < F; k++)   p += sh128[k] * W_dc[k * DWN + tid];
        for (int k = 0; k < HID; k++) p += sh1024[k] * W_down[k * DWN + tid];
        p /= (float)cnt;
        sp[tid] = p / (1.f + __expf(-p));
    }
    __syncthreads();
    {
        int o = tid * 4;
        float4 acc = *(const float4*)&b_up[o];
        for (int k = 0; k < DWN; k++) {
            float s = sp[k];
            float4 w = *(const float4*)&W_up[(size_t)k * HID + o];
            acc.x += s * w.x; acc.y += s * w.y; acc.z += s * w.z; acc.w += s * w.w;
        }
        *(float4*)&out[((size_t)(b * TP + t)) * HID + o] = acc;
    }
}

extern "C" void kernel_launch(void* const* d_in, const int* in_sizes, int n_in,
                              void* d_out, int out_size, void* d_ws, size_t ws_size,
                              hipStream_t stream) {
    const int*   graph_x   = (const int*)d_in[0];
    const int*   edge_idx  = (const int*)d_in[1];
    const int*   batch_ids = (const int*)d_in[2];
    const float* hidden    = (const float*)d_in[3];
    const int*   seq_len   = (const int*)d_in[4];
    const float* emb       = (const float*)d_in[5];
    const float* gat_W     = (const float*)d_in[6];
    const float* gat_as    = (const float*)d_in[7];
    const float* gat_ad    = (const float*)d_in[8];
    const float* gat_b     = (const float*)d_in[9];
    const float* W_down    = (const float*)d_in[10];
    const float* b_down    = (const float*)d_in[11];
    const float* W_dc      = (const float*)d_in[12];
    const float* b_dc      = (const float*)d_in[13];
    const float* W_up      = (const float*)d_in[14];
    const float* b_up      = (const float*)d_in[15];
    float* out = (float*)d_out;

    char* ws = (char*)d_ws;
    ushort* bufA   = (ushort*)(ws);                   // x bf16, 25,600,000 B
    ushort* hb     = (ushort*)(ws + 51200000);        // h bf16, 25,600,000 B
    float*  hs_src = (float*) (ws + 102400000);
    float*  hs_dst = (float*) (ws + 102800000);
    int*    counts = (int*)   (ws + 103200000);
    int*    indptr = (int*)   (ws + 103600000);
    int*    cursor = (int*)   (ws + 104000128);
    int*    srcs   = (int*)   (ws + 104400128);
    int*    bsum   = (int*)   (ws + 108000128);
    int*    boff   = (int*)   (ws + 108001128);
    int*    offs   = (int*)   (ws + 108002128);
    // bin tables overlay the hb region (h dead after last k_agg)
    float* s128   = (float*)(ws + 51200000);          // 131,072 B
    float* s1024  = (float*)(ws + 51200000 + 131072); // 1,048,576 B

    hipMemsetAsync(counts, 0, NN * sizeof(int), stream);
    k_offsets<<<(NN + 255) / 256, 256, 0, stream>>>(batch_ids, offs);
    k_embed<<<NN * 16 / 256, 256, 0, stream>>>(graph_x, emb, bufA);
    k_hist<<<(E2 + 255) / 256, 256, 0, stream>>>(edge_idx, counts);
    k_bsum<<<200, 256, 0, stream>>>(counts, bsum);
    k_boff<<<1, 64, 0, stream>>>(bsum, boff);
    k_scan<<<200, 256, 0, stream>>>(counts, boff, indptr, cursor);
    k_scatter<<<(E2 + 255) / 256, 256, 0, stream>>>(edge_idx, cursor, srcs);

    for (int l = 0; l < 3; l++) {
        k_gemm<<<(NN + 127) / 128, 256, 0, stream>>>(bufA, gat_W + l * F * F, gat_as + l * F,
                                                     gat_ad + l * F, hb, hs_src, hs_dst);
        k_agg<<<(NN + 3) / 4, 256, 0, stream>>>(hb, srcs, indptr, hs_src, hs_dst,
                                                gat_b + l * F, bufA, (l < 2) ? 1 : 0);
    }

    hipMemsetAsync((void*)s128, 0, 131072 + 1048576, stream);
    k_binsum_ctx<<<391, 256, 0, stream>>>(bufA, batch_ids, offs, seq_len, s128);
    k_binsum_hid<<<256, 256, 0, stream>>>(hidden, offs, seq_len, s1024);
    k_pool<<<NB * TP, 256, 0, stream>>>(s128, s1024, offs, seq_len,
                                        W_dc, b_dc, W_down, b_down, W_up, b_up, out);
}

// Round 6
// 422.101 us; speedup vs baseline: 3.9641x; 1.2706x over previous
//
#include <hip/hip_runtime.h>
#include <hip/hip_bf16.h>

#define NN 100000   // nodes
#define NE 800000   // edges (without self loops)
#define E2 900000   // edges + self loops
#define F  128      // KGE
#define NB 8        // batch
#define SEQ 1024
#define HID 1024
#define DWN 256
#define TP 32

typedef __attribute__((ext_vector_type(4))) float f32x4;
typedef __attribute__((ext_vector_type(8))) short s16x8;

__device__ __forceinline__ float BL(uint u) { return __uint_as_float(u << 16); }
__device__ __forceinline__ float BH(uint u) { return __uint_as_float(u & 0xffff0000u); }
__device__ __forceinline__ uint PK(float lo, float hi) {
    __hip_bfloat16 a = __float2bfloat16(lo);
    __hip_bfloat16 b = __float2bfloat16(hi);
    return (uint)(*(ushort*)&a) | ((uint)(*(ushort*)&b) << 16);
}
__device__ __forceinline__ ushort B1(float v) {
    __hip_bfloat16 a = __float2bfloat16(v);
    return *(ushort*)&a;
}

// ---------------- batch offsets from sorted batch_ids ----------------
__global__ void k_offsets(const int* __restrict__ bids, int* __restrict__ offs) {
    int n = blockIdx.x * 256 + threadIdx.x;
    if (n >= NN) return;
    int b = bids[n];
    if (n == 0) offs[0] = 0;
    else if (bids[n - 1] != b) offs[b] = n;
    if (n == NN - 1) offs[b + 1] = NN;
}

// ---------------- embedding gather: x[n] = bf16(emb[graph_x[n]]) ----------------
__global__ void k_embed(const int* __restrict__ gx, const float* __restrict__ emb,
                        ushort* __restrict__ x) {
    int i = blockIdx.x * 256 + threadIdx.x;   // over NN*16 chunks of 8 cols
    int n = i >> 4, c = i & 15;
    const float4* src = (const float4*)(emb + (size_t)gx[n] * F + c * 8);
    float4 a = src[0], b = src[1];
    uint4 o;
    o.x = PK(a.x, a.y); o.y = PK(a.z, a.w);
    o.z = PK(b.x, b.y); o.w = PK(b.z, b.w);
    *(uint4*)&x[(size_t)n * F + c * 8] = o;
}

// ---------------- W transpose+bf16: wt[l][col][k] = bf16(W[l][k][col]) ----------
__global__ void k_wconv(const float* __restrict__ W, ushort* __restrict__ wt) {
    int l = blockIdx.x >> 7, col = blockIdx.x & 127, k = threadIdx.x;
    wt[l * 16384 + col * 128 + k] = B1(W[l * 16384 + k * 128 + col]);
}

// ---------------- CSR build ----------------
__global__ void k_hist(const int* __restrict__ ei, int* __restrict__ counts) {
    int e = blockIdx.x * 256 + threadIdx.x;
    if (e >= E2) return;
    int dst = (e < NE) ? ei[NE + e] : (e - NE);
    atomicAdd(&counts[dst], 1);
}

__global__ void k_bsum(const int* __restrict__ counts, int* __restrict__ bsum) {
    __shared__ int red[256];
    int b = blockIdx.x, t = threadIdx.x;
    int base = b * 500;
    int s = 0;
    for (int i = t; i < 500; i += 256) s += counts[base + i];
    red[t] = s; __syncthreads();
    for (int o = 128; o > 0; o >>= 1) { if (t < o) red[t] += red[t + o]; __syncthreads(); }
    if (t == 0) bsum[b] = red[0];
}

__global__ void k_boff(const int* __restrict__ bsum, int* __restrict__ boff) {
    if (threadIdx.x == 0) {
        int r = 0;
        for (int i = 0; i < 200; i++) { boff[i] = r; r += bsum[i]; }
        boff[200] = r;
    }
}

__global__ __launch_bounds__(256) void k_scan(const int* __restrict__ counts,
                                              const int* __restrict__ boff,
                                              int* __restrict__ indptr,
                                              int* __restrict__ cursor) {
    __shared__ int sa[256], sb[256];
    int b = blockIdx.x, t = threadIdx.x;
    int base = b * 500;
    int i0 = t * 2, i1 = t * 2 + 1;
    int c0 = (i0 < 500) ? counts[base + i0] : 0;
    int c1 = (i1 < 500) ? counts[base + i1] : 0;
    sa[t] = c0 + c1;
    __syncthreads();
    int* src = sa; int* dst = sb;
    for (int off = 1; off < 256; off <<= 1) {
        int v = src[t];
        if (t >= off) v += src[t - off];
        dst[t] = v;
        __syncthreads();
        int* tmp = src; src = dst; dst = tmp;
    }
    int excl = src[t] - (c0 + c1) + boff[b];
    if (i0 < 500) { indptr[base + i0] = excl; cursor[base + i0] = excl; }
    if (i1 < 500) { indptr[base + i1] = excl + c0; cursor[base + i1] = excl + c0; }
    if (b == 199 && t == 0) indptr[NN] = E2;
}

__global__ void k_scatter(const int* __restrict__ ei, int* __restrict__ cursor,
                          int* __restrict__ srcs) {
    int e = blockIdx.x * 256 + threadIdx.x;
    if (e >= E2) return;
    int src, dst;
    if (e < NE) { src = ei[e]; dst = ei[NE + e]; }
    else        { src = dst = e - NE; }
    int pos = atomicAdd(&cursor[dst], 1);
    srcs[pos] = src;
}

// ---------------- MFMA GEMM: h = x @ W (bf16), fused hs epilogue ----------------
// 128x128 tile, 4 waves; wave: 32 rows (2 m-frags) x 128 cols (8 n-frags).
// A/W tiles in LDS as 16B chunks, XOR-swizzled: chunk_idx ^= (row&7) -> 2-way max.
__global__ __launch_bounds__(256) void k_gemm(
    const ushort* __restrict__ xb, const ushort* __restrict__ wt,
    const float* __restrict__ a_s, const float* __restrict__ a_d,
    ushort* __restrict__ hb, float* __restrict__ hs_src, float* __restrict__ hs_dst) {
    __shared__ uint4 As[128 * 16];
    __shared__ uint4 Bs[128 * 16];
    const int tid = threadIdx.x;
    const int wave = tid >> 6, lane = tid & 63;
    const int row0 = blockIdx.x * 128;
    const int lr = lane & 15, lg = lane >> 4;

    #pragma unroll
    for (int p = 0; p < 8; p++) {
        int id = p * 256 + tid;
        int row = id >> 4, c16 = id & 15;
        int rg = row0 + row; if (rg >= NN) rg = NN - 1;
        As[row * 16 + (c16 ^ (row & 7))] = *(const uint4*)&xb[(size_t)rg * F + c16 * 8];
        Bs[row * 16 + (c16 ^ (row & 7))] = *(const uint4*)&wt[row * F + c16 * 8];
    }
    __syncthreads();

    f32x4 acc[2][8];
    #pragma unroll
    for (int m = 0; m < 2; m++)
        #pragma unroll
        for (int n = 0; n < 8; n++) acc[m][n] = (f32x4){0.f, 0.f, 0.f, 0.f};

    #pragma unroll
    for (int kt = 0; kt < 4; kt++) {
        s16x8 a[2], b[8];
        #pragma unroll
        for (int m = 0; m < 2; m++) {
            int row = 32 * wave + 16 * m + lr;
            a[m] = *reinterpret_cast<const s16x8*>(&As[row * 16 + ((kt * 4 + lg) ^ (row & 7))]);
        }
        #pragma unroll
        for (int n = 0; n < 8; n++) {
            int col = 16 * n + lr;
            b[n] = *reinterpret_cast<const s16x8*>(&Bs[col * 16 + ((kt * 4 + lg) ^ (col & 7))]);
        }
        #pragma unroll
        for (int m = 0; m < 2; m++)
            #pragma unroll
            for (int n = 0; n < 8; n++)
                acc[m][n] = __builtin_amdgcn_mfma_f32_16x16x32_bf16(a[m], b[n], acc[m][n], 0, 0, 0);
    }

    float asv[8], adv[8];
    #pragma unroll
    for (int n = 0; n < 8; n++) { asv[n] = a_s[16 * n + lr]; adv[n] = a_d[16 * n + lr]; }

    #pragma unroll
    for (int m = 0; m < 2; m++) {
        #pragma unroll
        for (int r = 0; r < 4; r++) {
            int rg = row0 + 32 * wave + 16 * m + lg * 4 + r;
            bool ok = rg < NN;
            float ps = 0.f, pd = 0.f;
            #pragma unroll
            for (int n = 0; n < 8; n++) {
                float v = acc[m][n][r];
                if (ok) hb[(size_t)rg * F + 16 * n + lr] = B1(v);
                ps += v * asv[n]; pd += v * adv[n];
            }
            #pragma unroll
            for (int msk = 8; msk >= 1; msk >>= 1) {
                ps += __shfl_xor(ps, msk);
                pd += __shfl_xor(pd, msk);
            }
            if (ok && lr == 0) { hs_src[rg] = ps; hs_dst[rg] = pd; }
        }
    }
}

// ---------------- per-node GAT aggregation (softmax over in-edges) ----------------
__global__ __launch_bounds__(256) void k_agg(
    const ushort* __restrict__ hb, const int* __restrict__ srcs,
    const int* __restrict__ indptr, const float* __restrict__ hs_src,
    const float* __restrict__ hs_dst, const float* __restrict__ bias,
    ushort* __restrict__ xout, int do_relu) {
    __shared__ uint2 se[4][64];
    int wave = threadIdx.x >> 6, lane = threadIdx.x & 63;
    int i = blockIdx.x * 4 + wave;
    if (i >= NN) return;
    int p0 = indptr[i], p1 = indptr[i + 1];
    int deg = p1 - p0;
    float hd = hs_dst[i];
    float ax0 = 0.f, ay0 = 0.f, ax1 = 0.f, ay1 = 0.f;
    float ax2 = 0.f, ay2 = 0.f, ax3 = 0.f, ay3 = 0.f, dl = 0.f;

    if (deg <= 64) {
        int s = 0; float e = -1e30f;
        if (lane < deg) {
            s = srcs[p0 + lane];
            float t0 = hs_src[s] + hd;
            e = t0 > 0.f ? t0 : 0.2f * t0;
        }
        float m = e;
        #pragma unroll
        for (int o = 32; o > 0; o >>= 1) m = fmaxf(m, __shfl_xor(m, o));
        float ex = (lane < deg) ? __expf(e - m) : 0.f;
        dl = ex;
        se[wave][lane] = make_uint2((unsigned)s, __float_as_uint(ex));
        int j = 0;
        for (; j + 4 <= deg; j += 4) {
            uint2 q0 = se[wave][j + 0], q1 = se[wave][j + 1];
            uint2 q2 = se[wave][j + 2], q3 = se[wave][j + 3];
            uint h0 = ((const uint*)(hb + (size_t)q0.x * F))[lane];
            uint h1 = ((const uint*)(hb + (size_t)q1.x * F))[lane];
            uint h2 = ((const uint*)(hb + (size_t)q2.x * F))[lane];
            uint h3 = ((const uint*)(hb + (size_t)q3.x * F))[lane];
            float e0 = __uint_as_float(q0.y), e1 = __uint_as_float(q1.y);
            float e2 = __uint_as_float(q2.y), e3 = __uint_as_float(q3.y);
            ax0 += e0 * BL(h0); ay0 += e0 * BH(h0);
            ax1 += e1 * BL(h1); ay1 += e1 * BH(h1);
            ax2 += e2 * BL(h2); ay2 += e2 * BH(h2);
            ax3 += e3 * BL(h3); ay3 += e3 * BH(h3);
        }
        for (; j < deg; j++) {
            uint2 q = se[wave][j];
            uint h = ((const uint*)(hb + (size_t)q.x * F))[lane];
            float e0 = __uint_as_float(q.y);
            ax0 += e0 * BL(h); ay0 += e0 * BH(h);
        }
    } else {
        float m = -1e30f;
        for (int p = p0 + lane; p < p1; p += 64) {
            int s = srcs[p];
            float e = hs_src[s] + hd;
            e = e > 0.f ? e : 0.2f * e;
            m = fmaxf(m, e);
        }
        #pragma unroll
        for (int o = 32; o > 0; o >>= 1) m = fmaxf(m, __shfl_xor(m, o));
        for (int base = p0; base < p1; base += 64) {
            int cn = min(64, p1 - base);
            int s = 0; float ex = 0.f;
            if (lane < cn) {
                s = srcs[base + lane];
                float e = hs_src[s] + hd;
                e = e > 0.f ? e : 0.2f * e;
                ex = __expf(e - m);
            }
            dl += ex;
            se[wave][lane] = make_uint2((unsigned)s, __float_as_uint(ex));
            int j = 0;
            for (; j + 4 <= cn; j += 4) {
                uint2 q0 = se[wave][j + 0], q1 = se[wave][j + 1];
                uint2 q2 = se[wave][j + 2], q3 = se[wave][j + 3];
                uint h0 = ((const uint*)(hb + (size_t)q0.x * F))[lane];
                uint h1 = ((const uint*)(hb + (size_t)q1.x * F))[lane];
                uint h2 = ((const uint*)(hb + (size_t)q2.x * F))[lane];
                uint h3 = ((const uint*)(hb + (size_t)q3.x * F))[lane];
                float e0 = __uint_as_float(q0.y), e1 = __uint_as_float(q1.y);
                float e2 = __uint_as_float(q2.y), e3 = __uint_as_float(q3.y);
                ax0 += e0 * BL(h0); ay0 += e0 * BH(h0);
                ax1 += e1 * BL(h1); ay1 += e1 * BH(h1);
                ax2 += e2 * BL(h2); ay2 += e2 * BH(h2);
                ax3 += e3 * BL(h3); ay3 += e3 * BH(h3);
            }
            for (; j < cn; j++) {
                uint2 q = se[wave][j];
                uint h = ((const uint*)(hb + (size_t)q.x * F))[lane];
                float e0 = __uint_as_float(q.y);
                ax0 += e0 * BL(h); ay0 += e0 * BH(h);
            }
        }
    }
    float accx = (ax0 + ax1) + (ax2 + ax3);
    float accy = (ay0 + ay1) + (ay2 + ay3);
    #pragma unroll
    for (int o = 32; o > 0; o >>= 1) dl += __shfl_xor(dl, o);
    float inv = 1.f / dl;
    float2 b2 = ((const float2*)bias)[lane];
    float ox = accx * inv + b2.x;
    float oy = accy * inv + b2.y;
    if (do_relu) { ox = fmaxf(ox, 0.f); oy = fmaxf(oy, 0.f); }
    ((uint*)xout)[(size_t)i * 64 + lane] = PK(ox, oy);
}

// ---------------- bin sums: ctx rows (x3 bf16, 128 cols) ----------------
__global__ __launch_bounds__(256) void k_binsum_ctx(
    const ushort* __restrict__ x3, const int* __restrict__ bids,
    const int* __restrict__ offs, const int* __restrict__ seq_len,
    float* __restrict__ s128) {
    int wid = blockIdx.x * 4 + (threadIdx.x >> 6);
    int lane = threadIdx.x & 63;
    int r0 = wid * 64;
    if (r0 >= NN) return;
    int r1 = min(r0 + 64, NN);
    float ax = 0.f, ay = 0.f;
    int cur = -1;
    int cb = -1, off = 0, C = 0, L = 1;
    for (int r = r0; r < r1; r++) {
        int b = bids[r];
        if (b != cb) { cb = b; off = offs[b]; C = offs[b + 1] - off; L = C + seq_len[b]; }
        int q = r - off;
        int tmin = (q * TP) / L;
        int tmax = ((q + 1) * TP - 1) / L;
        uint v = ((const uint*)(x3 + (size_t)r * F))[lane];
        float vx = BL(v), vy = BH(v);
        int bin = b * TP + tmin;
        if (bin != cur) {
            if (cur >= 0) {
                atomicAdd(&s128[(size_t)cur * F + 2 * lane], ax);
                atomicAdd(&s128[(size_t)cur * F + 2 * lane + 1], ay);
            }
            cur = bin; ax = 0.f; ay = 0.f;
        }
        ax += vx; ay += vy;
        if (tmax != tmin) {
            atomicAdd(&s128[(size_t)(b * TP + tmax) * F + 2 * lane], vx);
            atomicAdd(&s128[(size_t)(b * TP + tmax) * F + 2 * lane + 1], vy);
        }
    }
    if (cur >= 0) {
        atomicAdd(&s128[(size_t)cur * F + 2 * lane], ax);
        atomicAdd(&s128[(size_t)cur * F + 2 * lane + 1], ay);
    }
}

// ---------------- bin sums: hidden rows (1024 cols), 8-row chunks ----------------
__global__ __launch_bounds__(256) void k_binsum_hid(
    const float* __restrict__ hidden, const int* __restrict__ offs,
    const int* __restrict__ seq_len, float* __restrict__ s1024) {
    int wid = blockIdx.x * 4 + (threadIdx.x >> 6);   // 0..1023
    int lane = threadIdx.x & 63;
    int b = wid >> 7;          // 128 chunks per batch
    int chunk = wid & 127;
    int sl = seq_len[b];
    int r0 = chunk * 8;
    if (r0 >= sl) return;
    int r1 = min(r0 + 8, sl);
    int C = offs[b + 1] - offs[b];
    int L = C + sl;
    float a[16];
    #pragma unroll
    for (int c = 0; c < 16; c++) a[c] = 0.f;
    int cur = -1;
    const float* hbase = hidden + (size_t)b * SEQ * HID;
    for (int r = r0; r < r1; r++) {
        int q = C + r;
        int tmin = (q * TP) / L;
        int tmax = ((q + 1) * TP - 1) / L;
        const float4* row = (const float4*)(hbase + (size_t)r * HID);
        float4 v0 = row[lane], v1 = row[64 + lane], v2 = row[128 + lane], v3 = row[192 + lane];
        int bin = b * TP + tmin;
        if (bin != cur) {
            if (cur >= 0) {
                float* dst = s1024 + (size_t)cur * HID;
                #pragma unroll
                for (int c = 0; c < 4; c++) atomicAdd(&dst[4 * lane + c], a[c]);
                #pragma unroll
                for (int c = 0; c < 4; c++) atomicAdd(&dst[256 + 4 * lane + c], a[4 + c]);
                #pragma unroll
                for (int c = 0; c < 4; c++) atomicAdd(&dst[512 + 4 * lane + c], a[8 + c]);
                #pragma unroll
                for (int c = 0; c < 4; c++) atomicAdd(&dst[768 + 4 * lane + c], a[12 + c]);
            }
            cur = bin;
            #pragma unroll
            for (int c = 0; c < 16; c++) a[c] = 0.f;
        }
        a[0] += v0.x; a[1] += v0.y; a[2] += v0.z; a[3] += v0.w;
        a[4] += v1.x; a[5] += v1.y; a[6] += v1.z; a[7] += v1.w;
        a[8] += v2.x; a[9] += v2.y; a[10] += v2.z; a[11] += v2.w;
        a[12] += v3.x; a[13] += v3.y; a[14] += v3.z; a[15] += v3.w;
        if (tmax != tmin) {
            float* dst = s1024 + (size_t)(b * TP + tmax) * HID;
            atomicAdd(&dst[4 * lane + 0], v0.x); atomicAdd(&dst[4 * lane + 1], v0.y);
            atomicAdd(&dst[4 * lane + 2], v0.z); atomicAdd(&dst[4 * lane + 3], v0.w);
            atomicAdd(&dst[256 + 4 * lane + 0], v1.x); atomicAdd(&dst[256 + 4 * lane + 1], v1.y);
            atomicAdd(&dst[256 + 4 * lane + 2], v1.z); atomicAdd(&dst[256 + 4 * lane + 3], v1.w);
            atomicAdd(&dst[512 + 4 * lane + 0], v2.x); atomicAdd(&dst[512 + 4 * lane + 1], v2.y);
            atomicAdd(&dst[512 + 4 * lane + 2], v2.z); atomicAdd(&dst[512 + 4 * lane + 3], v2.w);
            atomicAdd(&dst[768 + 4 * lane + 0], v3.x); atomicAdd(&dst[768 + 4 * lane + 1], v3.y);
            atomicAdd(&dst[768 + 4 * lane + 2], v3.z); atomicAdd(&dst[768 + 4 * lane + 3], v3.w);
        }
    }
    if (cur >= 0) {
        float* dst = s1024 + (size_t)cur * HID;
        #pragma unroll
        for (int c = 0; c < 4; c++) atomicAdd(&dst[4 * lane + c], a[c]);
        #pragma unroll
        for (int c = 0; c < 4; c++) atomicAdd(&dst[256 + 4 * lane + c], a[4 + c]);
        #pragma unroll
        for (int c = 0; c < 4; c++) atomicAdd(&dst[512 + 4 * lane + c], a[8 + c]);
        #pragma unroll
        for (int c = 0; c < 4; c++) atomicAdd(&dst[768 + 4 * lane + c], a[12 + c]);
    }
}

// ---------------- sp[bin][c] = silu(pooled) : 4-way k-split ----------------
__global__ __launch_bounds__(1024) void k_sp(
    const float* __restrict__ s128, const float* __restrict__ s1024,
    const int* __restrict__ offs, const int* __restrict__ seq_len,
    const float* __restrict__ W_dc, const float* __restrict__ b_dc,
    const float* __restrict__ W_down, const float* __restrict__ b_down,
    float* __restrict__ sp) {
    __shared__ float red[4][DWN];
    int bin = blockIdx.x;
    int b = bin >> 5, t = bin & 31;
    int c = threadIdx.x & 255, ks = threadIdx.x >> 8;
    int C = offs[b + 1] - offs[b];
    int sl = seq_len[b];
    int L = C + sl;
    int start = (t * L) / TP;
    int end = ((t + 1) * L + TP - 1) / TP;
    int cnt = end - start;
    int ce = min(end, C);
    int n_ctx = max(ce - start, 0);
    int n_hs = max(end - C, 0) - max(start - C, 0);
    float p = 0.f;
    int k0 = ks * 288, k1 = k0 + 288;
    for (int k = k0; k < k1; k++) {
        if (k < F) p += s128[(size_t)bin * F + k] * W_dc[k * DWN + c];
        else {
            int kk = k - F;
            p += s1024[(size_t)bin * HID + kk] * W_down[kk * DWN + c];
        }
    }
    red[ks][c] = p;
    __syncthreads();
    if (ks == 0) {
        p = (red[0][c] + red[1][c]) + (red[2][c] + red[3][c])
            + (float)n_ctx * b_dc[c] + (float)n_hs * b_down[c];
        p /= (float)cnt;
        sp[(size_t)bin * DWN + c] = p / (1.f + __expf(-p));
    }
}

// ---------------- out[bin][o] = sp[bin] . W_up[:,o] + b_up ----------------
__global__ __launch_bounds__(256) void k_up(
    const float* __restrict__ sp, const float* __restrict__ W_up,
    const float* __restrict__ b_up, float* __restrict__ out) {
    __shared__ float s[DWN];
    int bin = blockIdx.x >> 2, q = blockIdx.x & 3;
    int tid = threadIdx.x;
    s[tid] = sp[(size_t)bin * DWN + tid];
    __syncthreads();
    int o = q * 256 + tid;
    float a0 = 0.f, a1 = 0.f, a2 = 0.f, a3 = 0.f;
    #pragma unroll 4
    for (int k = 0; k < DWN; k += 4) {
        a0 += s[k + 0] * W_up[(size_t)(k + 0) * HID + o];
        a1 += s[k + 1] * W_up[(size_t)(k + 1) * HID + o];
        a2 += s[k + 2] * W_up[(size_t)(k + 2) * HID + o];
        a3 += s[k + 3] * W_up[(size_t)(k + 3) * HID + o];
    }
    out[(size_t)bin * HID + o] = (a0 + a1) + (a2 + a3) + b_up[o];
}

extern "C" void kernel_launch(void* const* d_in, const int* in_sizes, int n_in,
                              void* d_out, int out_size, void* d_ws, size_t ws_size,
                              hipStream_t stream) {
    const int*   graph_x   = (const int*)d_in[0];
    const int*   edge_idx  = (const int*)d_in[1];
    const int*   batch_ids = (const int*)d_in[2];
    const float* hidden    = (const float*)d_in[3];
    const int*   seq_len   = (const int*)d_in[4];
    const float* emb       = (const float*)d_in[5];
    const float* gat_W     = (const float*)d_in[6];
    const float* gat_as    = (const float*)d_in[7];
    const float* gat_ad    = (const float*)d_in[8];
    const float* gat_b     = (const float*)d_in[9];
    const float* W_down    = (const float*)d_in[10];
    const float* b_down    = (const float*)d_in[11];
    const float* W_dc      = (const float*)d_in[12];
    const float* b_dc      = (const float*)d_in[13];
    const float* W_up      = (const float*)d_in[14];
    const float* b_up      = (const float*)d_in[15];
    float* out = (float*)d_out;

    char* ws = (char*)d_ws;
    ushort* bufA   = (ushort*)(ws);                   // x bf16, 25,600,000 B
    ushort* Wt     = (ushort*)(ws + 26000000);        // 98,304 B
    ushort* hb     = (ushort*)(ws + 51200000);        // h bf16, 25,600,000 B
    float*  s128   = (float*) (ws + 80000000);        // 131,072 B
    float*  s1024  = (float*) (ws + 80131072);        // 1,048,576 B
    float*  sp     = (float*) (ws + 81179648);        // 262,144 B
    float*  hs_src = (float*) (ws + 102400000);
    float*  hs_dst = (float*) (ws + 102800000);
    int*    counts = (int*)   (ws + 103200000);
    int*    indptr = (int*)   (ws + 103600000);
    int*    cursor = (int*)   (ws + 104000128);
    int*    srcs   = (int*)   (ws + 104400128);
    int*    bsum   = (int*)   (ws + 108000128);
    int*    boff   = (int*)   (ws + 108001128);
    int*    offs   = (int*)   (ws + 108002128);

    hipMemsetAsync(counts, 0, NN * sizeof(int), stream);
    k_offsets<<<(NN + 255) / 256, 256, 0, stream>>>(batch_ids, offs);
    k_embed<<<NN * 16 / 256, 256, 0, stream>>>(graph_x, emb, bufA);
    k_wconv<<<384, 128, 0, stream>>>(gat_W, Wt);
    k_hist<<<(E2 + 255) / 256, 256, 0, stream>>>(edge_idx, counts);
    k_bsum<<<200, 256, 0, stream>>>(counts, bsum);
    k_boff<<<1, 64, 0, stream>>>(bsum, boff);
    k_scan<<<200, 256, 0, stream>>>(counts, boff, indptr, cursor);
    k_scatter<<<(E2 + 255) / 256, 256, 0, stream>>>(edge_idx, cursor, srcs);

    for (int l = 0; l < 3; l++) {
        k_gemm<<<(NN + 127) / 128, 256, 0, stream>>>(bufA, Wt + l * F * F, gat_as + l * F,
                                                     gat_ad + l * F, hb, hs_src, hs_dst);
        k_agg<<<(NN + 3) / 4, 256, 0, stream>>>(hb, srcs, indptr, hs_src, hs_dst,
                                                gat_b + l * F, bufA, (l < 2) ? 1 : 0);
    }

    hipMemsetAsync((void*)s128, 0, 131072 + 1048576, stream);
    k_binsum_ctx<<<391, 256, 0, stream>>>(bufA, batch_ids, offs, seq_len, s128);
    k_binsum_hid<<<256, 256, 0, stream>>>(hidden, offs, seq_len, s1024);
    k_sp<<<NB * TP, 1024, 0, stream>>>(s128, s1024, offs, seq_len,
                                       W_dc, b_dc, W_down, b_down, sp);
    k_up<<<NB * TP * 4, 256, 0, stream>>>(sp, W_up, b_up, out);
}